// Round 7
// baseline (335.938 us; speedup 1.0000x reference)
//
#include <hip/hip_runtime.h>

#define EPS_BN 1e-5f

// ---------------- three_nn (unchanged, verified r3) ----------------
__global__ __launch_bounds__(512) void three_nn_par_kernel(
    const float* __restrict__ unknown,  // (B, Nu, 3)
    const float* __restrict__ known,    // (B, Nk, 3)
    int Nu, int Nk, int* __restrict__ idx, float* __restrict__ wgt)
{
    const int NSEG = 16;
    __shared__ float kl[3 * 1024];
    __shared__ float sd[NSEG][32][3];
    __shared__ int   si[NSEG][32][3];
    const int b = blockIdx.y;
    for (int i = threadIdx.x; i < Nk * 3; i += 512) kl[i] = known[(size_t)b * Nk * 3 + i];
    __syncthreads();
    const int u   = threadIdx.x & 31;
    const int seg = threadIdx.x >> 5;
    const int n   = blockIdx.x * 32 + u;
    const float* up = unknown + ((size_t)b * Nu + n) * 3;
    const float ux = up[0], uy = up[1], uz = up[2];
    float d0 = 1e30f, d1 = 1e30f, d2 = 1e30f;
    int i0 = 0, i1 = 0, i2 = 0;
    const int klo = seg * (Nk / NSEG), khi = klo + Nk / NSEG;
    for (int k = klo; k < khi; ++k) {
        float dx = __fsub_rn(ux, kl[3 * k + 0]);
        float dy = __fsub_rn(uy, kl[3 * k + 1]);
        float dz = __fsub_rn(uz, kl[3 * k + 2]);
        float d = __fadd_rn(__fadd_rn(__fmul_rn(dx, dx), __fmul_rn(dy, dy)), __fmul_rn(dz, dz));
        if (d < d0)      { d2 = d1; i2 = i1; d1 = d0; i1 = i0; d0 = d; i0 = k; }
        else if (d < d1) { d2 = d1; i2 = i1; d1 = d;  i1 = k; }
        else if (d < d2) { d2 = d;  i2 = k; }
    }
    sd[seg][u][0] = d0; sd[seg][u][1] = d1; sd[seg][u][2] = d2;
    si[seg][u][0] = i0; si[seg][u][1] = i1; si[seg][u][2] = i2;
    __syncthreads();
    if (threadIdx.x < 32) {
        float m0 = 1e30f, m1 = 1e30f, m2 = 1e30f;
        int j0 = 0, j1 = 0, j2 = 0;
        for (int s = 0; s < NSEG; ++s)
            for (int c = 0; c < 3; ++c) {
                float d = sd[s][u][c];
                int ii = si[s][u][c];
                if (d < m0)      { m2 = m1; j2 = j1; m1 = m0; j1 = j0; m0 = d; j0 = ii; }
                else if (d < m1) { m2 = m1; j2 = j1; m1 = d;  j1 = ii; }
                else if (d < m2) { m2 = d;  j2 = ii; }
            }
        float w0 = 1.f / (m0 + 1e-8f), w1 = 1.f / (m1 + 1e-8f), w2 = 1.f / (m2 + 1e-8f);
        float s = w0 + w1 + w2;
        size_t base = ((size_t)b * Nu + n) * 3;
        idx[base + 0] = j0; idx[base + 1] = j1; idx[base + 2] = j2;
        wgt[base + 0] = w0 / s; wgt[base + 1] = w1 / s; wgt[base + 2] = w2 / s;
    }
}

// ---------------- interp: c-loop inside, idx/wgt loaded once ----------------
__global__ __launch_bounds__(256) void interp_kernel(
    const float* __restrict__ feat,                              // (NB, C, Ns)
    const int* __restrict__ idx, const float* __restrict__ wgt,  // (B, Nu, 3)
    float* __restrict__ out,                                     // (NB, C, Nu)
    int C, int Ns, int Nu, int Q)
{
    int n = blockIdx.x * 256 + threadIdx.x;
    int nb = blockIdx.y;
    int b = nb / Q;
    size_t nnb = ((size_t)b * Nu + n) * 3;
    int j0 = idx[nnb], j1 = idx[nnb + 1], j2 = idx[nnb + 2];
    float w0 = wgt[nnb], w1 = wgt[nnb + 1], w2 = wgt[nnb + 2];
    const float* f = feat + (size_t)nb * C * Ns;
    float* op = out + (size_t)nb * C * Nu + n;
#pragma unroll 4
    for (int c = 0; c < C; ++c) {
        const float* fr = f + (size_t)c * Ns;
        op[(size_t)c * Nu] = w0 * fr[j0] + w1 * fr[j1] + w2 * fr[j2];
    }
}

// ---------------- weight prep: transpose + fold BN scale ----------------
struct LayerDesc {
    const float* W; const float* b; const float* bn;
    float* wt; float* shb; int O; int C;
};
struct PrepArgs { LayerDesc l[9]; };

__global__ __launch_bounds__(256) void prep_kernel(PrepArgs a) {
    LayerDesc d = a.l[blockIdx.y];
    int total = d.O * d.C;
    for (int i = blockIdx.x * 256 + threadIdx.x; i < total; i += gridDim.x * 256) {
        int c = i / d.O, o = i - (i / d.O) * d.O;
        float sc = 1.f;
        if (d.bn) { float g = d.bn[o], v = d.bn[3 * d.O + o]; sc = g * rsqrtf(v + EPS_BN); }
        d.wt[i] = d.W[(size_t)o * d.C + c] * sc;
    }
    for (int o = blockIdx.x * 256 + threadIdx.x; o < d.O; o += gridDim.x * 256) {
        float sc = 1.f, sh = 0.f;
        if (d.bn) {
            float g = d.bn[o], be = d.bn[d.O + o], m = d.bn[2 * d.O + o], v = d.bn[3 * d.O + o];
            sc = g * rsqrtf(v + EPS_BN); sh = be - m * sc;
        }
        d.shb[o] = d.b[o] * sc + sh;
    }
}

// ---------------- conv: LDS weight slice, FMA-bound pipe mix ----
// y = relu( sum_c Wt[c][o] * x[c][n] + shb[o] )   (BN scale pre-folded in Wt)
// BLK threads; each owns VEC n-points (float-VEC loads) and OT outputs.
// Per c: OT/4 ds_read_b128 (broadcast) + OT*VEC FMAs -> FMA:LDS >= 2.6:1.
template <int BLK, int C0, int C1, int O, int OT, int VEC, bool RELU>
__global__ __launch_bounds__(BLK) void conv_tpl(
    const float* __restrict__ src0, int qdiv0,
    const float* __restrict__ src1, int qdiv1,
    const float* __restrict__ Wt,   // [C0+C1][O]
    const float* __restrict__ shb,  // [O]
    float* __restrict__ outp, int N)
{
    constexpr int CT = C0 + C1;
    static_assert(OT % 4 == 0 || OT < 4, "OT float4 grouping");
    __shared__ __align__(16) float wlds[CT * OT];
    const int tid = threadIdx.x;
    const int oBase = blockIdx.y * OT;
    const int nb = blockIdx.z;
    const int n0 = (blockIdx.x * BLK + tid) * VEC;

    for (int i = tid; i < CT * OT; i += BLK)
        wlds[i] = Wt[(size_t)(i / OT) * O + oBase + (i % OT)];
    __syncthreads();

    const float* s0 = src0 + (size_t)(nb / qdiv0) * C0 * N + n0;
    const float* s1 = (C1 > 0) ? (src1 + (size_t)(nb / qdiv1) * C1 * N + n0) : nullptr;

    float acc[OT][VEC];
#pragma unroll
    for (int ol = 0; ol < OT; ++ol)
#pragma unroll
        for (int j = 0; j < VEC; ++j) acc[ol][j] = 0.f;

    auto rowp = [&](int c) -> const float* {
        if constexpr (C1 == 0) return s0 + (size_t)c * N;
        else return (c < C0) ? (s0 + (size_t)c * N) : (s1 + (size_t)(c - C0) * N);
    };
    auto loadrow = [&](float (&x)[VEC], int c) {
        const float* p = rowp(c);
        if constexpr (VEC == 4) {
            float4 t = *reinterpret_cast<const float4*>(p);
            x[0] = t.x; x[1] = t.y; x[2] = t.z; x[3] = t.w;
        } else if constexpr (VEC == 2) {
            float2 t = *reinterpret_cast<const float2*>(p);
            x[0] = t.x; x[1] = t.y;
        } else {
            x[0] = *p;
        }
    };
    auto comprow = [&](const float (&x)[VEC], int c) {
        if constexpr (OT >= 4) {
#pragma unroll
            for (int g = 0; g < OT / 4; ++g) {
                float4 wv = *reinterpret_cast<const float4*>(&wlds[c * OT + g * 4]);
                float ww[4] = {wv.x, wv.y, wv.z, wv.w};
#pragma unroll
                for (int r = 0; r < 4; ++r)
#pragma unroll
                    for (int j = 0; j < VEC; ++j)
                        acc[g * 4 + r][j] += ww[r] * x[j];
            }
        } else {
#pragma unroll
            for (int ol = 0; ol < OT; ++ol) {
                float w = wlds[c * OT + ol];
#pragma unroll
                for (int j = 0; j < VEC; ++j) acc[ol][j] += w * x[j];
            }
        }
    };
    auto loadg = [&](float (&buf)[4][VEC], int c) {
#pragma unroll
        for (int q = 0; q < 4; ++q) loadrow(buf[q], c + q);
    };
    auto compg = [&](const float (&buf)[4][VEC], int c) {
#pragma unroll
        for (int q = 0; q < 4; ++q) comprow(buf[q], c + q);
    };

    if constexpr (CT == 3) {
        float xs[3][VEC];
        loadrow(xs[0], 0); loadrow(xs[1], 1); loadrow(xs[2], 2);
        comprow(xs[0], 0); comprow(xs[1], 1); comprow(xs[2], 2);
    } else {
        static_assert(CT % 8 == 0 || CT % 8 == 4, "CT pipeline tail");
        float xa[4][VEC], xb[4][VEC];
        loadg(xa, 0); loadg(xb, 4);
        int c = 0;
#pragma unroll 1
        for (; c + 16 <= CT; c += 8) {
            compg(xa, c);     loadg(xa, c + 8);
            compg(xb, c + 4); loadg(xb, c + 12);
        }
        compg(xa, c);
        if constexpr (CT % 8 == 4) {
            loadg(xa, c + 8);
            compg(xb, c + 4);
            compg(xa, c + 8);
        } else {
            compg(xb, c + 4);
        }
    }

#pragma unroll
    for (int ol = 0; ol < OT; ++ol) {
        int o = oBase + ol;
        float sb = shb[o];
        float res[VEC];
#pragma unroll
        for (int j = 0; j < VEC; ++j) {
            float y = acc[ol][j] + sb;
            if constexpr (RELU) y = fmaxf(y, 0.f);
            res[j] = y;
        }
        float* op = outp + ((size_t)nb * O + o) * N + n0;
        if constexpr (VEC == 4) {
            float4 t; t.x = res[0]; t.y = res[1]; t.z = res[2]; t.w = res[3];
            *reinterpret_cast<float4*>(op) = t;
        } else if constexpr (VEC == 2) {
            float2 t; t.x = res[0]; t.y = res[1];
            *reinterpret_cast<float2*>(op) = t;
        } else {
            *op = res[0];
        }
    }
}

extern "C" void kernel_launch(void* const* d_in, const int* in_sizes, int n_in,
                              void* d_out, int out_size, void* d_ws, size_t ws_size,
                              hipStream_t stream) {
    const int B = 2, Q = 16, N0 = 4096, N1 = 1024, N2 = 256;
    const int I1 = 144, I2 = 72, I3 = 36;
    const int NB = B * Q;  // 32

    const float* x     = (const float*)d_in[0];   // (B, 288, N2)
    const float* mask  = (const float*)d_in[1];   // (NB, 8, N2)
    const float* sa0f  = (const float*)d_in[2];   // (B, 3, N0)
    const float* sa1f  = (const float*)d_in[3];   // (B, 128, N1)
    const float* xyz0  = (const float*)d_in[4];   // (B, N0, 3)
    const float* xyz1  = (const float*)d_in[5];   // (B, N1, 3)
    const float* xyz2  = (const float*)d_in[6];   // (B, N2, 3)

    float* ws = (float*)d_ws;
    size_t off = 0;
    auto alloc = [&](size_t n) { size_t p = off; off += (n + 15) & ~(size_t)15; return p; };

    size_t f0b   = alloc((size_t)B * I2 * N0);
    size_t f1b   = alloc((size_t)B * I1 * N1);
    size_t wgt1  = alloc((size_t)B * N1 * 3);
    size_t wgt2  = alloc((size_t)B * N0 * 3);
    size_t idx1  = alloc((size_t)B * N1 * 3);
    size_t idx2  = alloc((size_t)B * N0 * 3);
    size_t slotA = alloc((size_t)NB * I2 * N0);   // h1 / interp1 / interp2
    size_t slotB = alloc((size_t)NB * I2 * N0);   // h2 / h3 / h5
    size_t slotC = alloc((size_t)NB * I3 * N0);   // h4 / h6
    size_t wt1 = alloc(296 * 296), sb1 = alloc(296);
    size_t wt2 = alloc(296 * 144), sb2 = alloc(144);
    size_t wt3 = alloc(288 * 144), sb3 = alloc(144);
    size_t wt4 = alloc(144 * 72),  sb4 = alloc(72);
    size_t wt5 = alloc(144 * 72),  sb5 = alloc(72);
    size_t wt6 = alloc(72 * 36),   sb6 = alloc(36);
    size_t wto = alloc(36),        sbo = alloc(16);
    size_t wa1 = alloc(3 * 72),    sa1b = alloc(72);
    size_t wa2 = alloc(128 * 144), sa2b = alloc(144);
    (void)ws_size; (void)in_sizes; (void)n_in;

    auto din = [&](int i) { return (const float*)d_in[i]; };

    PrepArgs pa;
    pa.l[0] = { din(7),  din(8),  din(9),  ws + wt1, ws + sb1, 296, 296 };
    pa.l[1] = { din(10), din(11), din(12), ws + wt2, ws + sb2, 144, 296 };
    pa.l[2] = { din(17), din(18), din(19), ws + wt3, ws + sb3, 144, 288 };
    pa.l[3] = { din(20), din(21), din(22), ws + wt4, ws + sb4, 72, 144 };
    pa.l[4] = { din(23), din(24), din(25), ws + wt5, ws + sb5, 72, 144 };
    pa.l[5] = { din(26), din(27), din(28), ws + wt6, ws + sb6, 36, 72 };
    pa.l[6] = { din(29), din(30), nullptr, ws + wto, ws + sbo, 1, 36 };
    pa.l[7] = { din(13), din(14), nullptr, ws + wa1, ws + sa1b, 72, 3 };
    pa.l[8] = { din(15), din(16), nullptr, ws + wa2, ws + sa2b, 144, 128 };
    prep_kernel<<<dim3(16, 9), 256, 0, stream>>>(pa);

    // three_nn (per-b)
    three_nn_par_kernel<<<dim3(N1 / 32, B), dim3(512), 0, stream>>>(
        xyz1, xyz2, N1, N2, (int*)(ws + idx1), ws + wgt1);
    three_nn_par_kernel<<<dim3(N0 / 32, B), dim3(512), 0, stream>>>(
        xyz0, xyz1, N0, N1, (int*)(ws + idx2), ws + wgt2);

    // adapters (per-b)
    conv_tpl<64, 3, 0, 72, 8, 4, false><<<dim3(16, 9, B), 64, 0, stream>>>(
        sa0f, 1, nullptr, 1, ws + wa1, ws + sa1b, ws + f0b, N0);
    conv_tpl<64, 128, 0, 144, 8, 4, false><<<dim3(4, 18, B), 64, 0, stream>>>(
        sa1f, 1, nullptr, 1, ws + wa2, ws + sa2b, ws + f1b, N1);

    // h1 = layer1(concat(x, mask)) : (NB, 296, 256) -> slotA   [1184 blocks]
    conv_tpl<64, 288, 8, 296, 8, 4, true><<<dim3(1, 37, NB), 64, 0, stream>>>(
        x, Q, mask, 1, ws + wt1, ws + sb1, ws + slotA, N2);
    // h2 : (NB, 144, 256) -> slotB   [576 blocks]
    conv_tpl<64, 296, 0, 144, 8, 4, true><<<dim3(1, 18, NB), 64, 0, stream>>>(
        ws + slotA, 1, nullptr, 1, ws + wt2, ws + sb2, ws + slotB, N2);

    // interp1: h2 (Ns=256) -> (NB, 144, 1024) -> slotA
    interp_kernel<<<dim3(N1 / 256, NB), 256, 0, stream>>>(
        ws + slotB, (const int*)(ws + idx1), ws + wgt1, ws + slotA, I1, N2, N1, Q);

    // h3 = fp1_layer1(concat(interp1, f1)) -> slotB   [576 blocks]
    conv_tpl<256, 144, 144, 144, 8, 4, true><<<dim3(1, 18, NB), 256, 0, stream>>>(
        ws + slotA, 1, ws + f1b, Q, ws + wt3, ws + sb3, ws + slotB, N1);
    // h4 -> slotC   [576 blocks]
    conv_tpl<256, 144, 0, 72, 4, 4, true><<<dim3(1, 18, NB), 256, 0, stream>>>(
        ws + slotB, 1, nullptr, 1, ws + wt4, ws + sb4, ws + slotC, N1);

    // interp2: h4 (Ns=1024) -> (NB, 72, 4096) -> slotA
    interp_kernel<<<dim3(N0 / 256, NB), 256, 0, stream>>>(
        ws + slotC, (const int*)(ws + idx2), ws + wgt2, ws + slotA, I2, N1, N0, Q);

    // h5 = fp2_layer1(concat(interp2, f0)) -> slotB   [768 blocks]
    conv_tpl<256, 72, 72, 72, 12, 4, true><<<dim3(4, 6, NB), 256, 0, stream>>>(
        ws + slotA, 1, ws + f0b, Q, ws + wt5, ws + sb5, ws + slotB, N0);
    // h6 -> slotC   [1152 blocks]
    conv_tpl<256, 72, 0, 36, 4, 4, true><<<dim3(4, 9, NB), 256, 0, stream>>>(
        ws + slotB, 1, nullptr, 1, ws + wt6, ws + sb6, ws + slotC, N0);

    // out = out_w @ h6 + out_b -> d_out (fp32)   [128 blocks]
    conv_tpl<256, 36, 0, 1, 1, 4, false><<<dim3(4, 1, NB), 256, 0, stream>>>(
        ws + slotC, 1, nullptr, 1, ws + wto, ws + sbo, (float*)d_out, N0);
}

// Round 8
// 295.310 us; speedup vs baseline: 1.1376x; 1.1376x over previous
//
#include <hip/hip_runtime.h>

#define EPS_BN 1e-5f

// ---------------- three_nn (unchanged, verified r3) ----------------
__global__ __launch_bounds__(512) void three_nn_par_kernel(
    const float* __restrict__ unknown,  // (B, Nu, 3)
    const float* __restrict__ known,    // (B, Nk, 3)
    int Nu, int Nk, int* __restrict__ idx, float* __restrict__ wgt)
{
    const int NSEG = 16;
    __shared__ float kl[3 * 1024];
    __shared__ float sd[NSEG][32][3];
    __shared__ int   si[NSEG][32][3];
    const int b = blockIdx.y;
    for (int i = threadIdx.x; i < Nk * 3; i += 512) kl[i] = known[(size_t)b * Nk * 3 + i];
    __syncthreads();
    const int u   = threadIdx.x & 31;
    const int seg = threadIdx.x >> 5;
    const int n   = blockIdx.x * 32 + u;
    const float* up = unknown + ((size_t)b * Nu + n) * 3;
    const float ux = up[0], uy = up[1], uz = up[2];
    float d0 = 1e30f, d1 = 1e30f, d2 = 1e30f;
    int i0 = 0, i1 = 0, i2 = 0;
    const int klo = seg * (Nk / NSEG), khi = klo + Nk / NSEG;
    for (int k = klo; k < khi; ++k) {
        float dx = __fsub_rn(ux, kl[3 * k + 0]);
        float dy = __fsub_rn(uy, kl[3 * k + 1]);
        float dz = __fsub_rn(uz, kl[3 * k + 2]);
        float d = __fadd_rn(__fadd_rn(__fmul_rn(dx, dx), __fmul_rn(dy, dy)), __fmul_rn(dz, dz));
        if (d < d0)      { d2 = d1; i2 = i1; d1 = d0; i1 = i0; d0 = d; i0 = k; }
        else if (d < d1) { d2 = d1; i2 = i1; d1 = d;  i1 = k; }
        else if (d < d2) { d2 = d;  i2 = k; }
    }
    sd[seg][u][0] = d0; sd[seg][u][1] = d1; sd[seg][u][2] = d2;
    si[seg][u][0] = i0; si[seg][u][1] = i1; si[seg][u][2] = i2;
    __syncthreads();
    if (threadIdx.x < 32) {
        float m0 = 1e30f, m1 = 1e30f, m2 = 1e30f;
        int j0 = 0, j1 = 0, j2 = 0;
        for (int s = 0; s < NSEG; ++s)
            for (int c = 0; c < 3; ++c) {
                float d = sd[s][u][c];
                int ii = si[s][u][c];
                if (d < m0)      { m2 = m1; j2 = j1; m1 = m0; j1 = j0; m0 = d; j0 = ii; }
                else if (d < m1) { m2 = m1; j2 = j1; m1 = d;  j1 = ii; }
                else if (d < m2) { m2 = d;  j2 = ii; }
            }
        float w0 = 1.f / (m0 + 1e-8f), w1 = 1.f / (m1 + 1e-8f), w2 = 1.f / (m2 + 1e-8f);
        float s = w0 + w1 + w2;
        size_t base = ((size_t)b * Nu + n) * 3;
        idx[base + 0] = j0; idx[base + 1] = j1; idx[base + 2] = j2;
        wgt[base + 0] = w0 / s; wgt[base + 1] = w1 / s; wgt[base + 2] = w2 / s;
    }
}

// ---------------- interp: c-loop inside, idx/wgt loaded once ----------------
__global__ __launch_bounds__(256) void interp_kernel(
    const float* __restrict__ feat,                              // (NB, C, Ns)
    const int* __restrict__ idx, const float* __restrict__ wgt,  // (B, Nu, 3)
    float* __restrict__ out,                                     // (NB, C, Nu)
    int C, int Ns, int Nu, int Q)
{
    int n = blockIdx.x * 256 + threadIdx.x;
    int nb = blockIdx.y;
    int b = nb / Q;
    size_t nnb = ((size_t)b * Nu + n) * 3;
    int j0 = idx[nnb], j1 = idx[nnb + 1], j2 = idx[nnb + 2];
    float w0 = wgt[nnb], w1 = wgt[nnb + 1], w2 = wgt[nnb + 2];
    const float* f = feat + (size_t)nb * C * Ns;
    float* op = out + (size_t)nb * C * Nu + n;
#pragma unroll 4
    for (int c = 0; c < C; ++c) {
        const float* fr = f + (size_t)c * Ns;
        op[(size_t)c * Nu] = w0 * fr[j0] + w1 * fr[j1] + w2 * fr[j2];
    }
}

// ---------------- weight prep: transpose + fold BN scale ----------------
struct LayerDesc {
    const float* W; const float* b; const float* bn;
    float* wt; float* shb; int O; int C;
};
struct PrepArgs { LayerDesc l[8]; };

__global__ __launch_bounds__(256) void prep_kernel(PrepArgs a) {
    LayerDesc d = a.l[blockIdx.y];
    int total = d.O * d.C;
    for (int i = blockIdx.x * 256 + threadIdx.x; i < total; i += gridDim.x * 256) {
        int c = i / d.O, o = i - (i / d.O) * d.O;
        float sc = 1.f;
        if (d.bn) { float g = d.bn[o], v = d.bn[3 * d.O + o]; sc = g * rsqrtf(v + EPS_BN); }
        d.wt[i] = d.W[(size_t)o * d.C + c] * sc;
    }
    for (int o = blockIdx.x * 256 + threadIdx.x; o < d.O; o += gridDim.x * 256) {
        float sc = 1.f, sh = 0.f;
        if (d.bn) {
            float g = d.bn[o], be = d.bn[d.O + o], m = d.bn[2 * d.O + o], v = d.bn[3 * d.O + o];
            sc = g * rsqrtf(v + EPS_BN); sh = be - m * sc;
        }
        d.shb[o] = d.b[o] * sc + sh;
    }
}

// ---------------- conv: LDS weight slice, 1-wave blocks, XCD swizzle ----
// y = act( sum_c Wt[c][o]*x[c][n] + (USE_BASE ? base[b][o][n] : shb[o]) )
// SWZ: flat grid, o-tile innermost per XCD -> input HBM-fetched once.
template <int BLK, int C0, int O, int OT, int VEC, bool RELU, bool USE_BASE, bool SWZ>
__global__ __launch_bounds__(BLK) void conv_tpl(
    const float* __restrict__ src0, int qdiv0,
    const float* __restrict__ Wt,   // rows [c][O] (pre-offset to this c-range)
    const float* __restrict__ shb,  // [O]
    const float* __restrict__ basep, int qdivb,  // (Bb, O, N)
    float* __restrict__ outp, int N, int GX, int GY)
{
    constexpr int CT = C0;
    __shared__ __align__(16) float wlds[CT * OT];
    const int tid = threadIdx.x;

    int nt, ot, nb;
    if constexpr (SWZ) {
        int f = blockIdx.x;
        int J = gridDim.x >> 3;
        int j = (f & 7) * J + (f >> 3);
        ot = j % GY; int r = j / GY;
        nt = r % GX; nb = r / GX;
    } else {
        nt = blockIdx.x; ot = blockIdx.y; nb = blockIdx.z;
    }
    const int oBase = ot * OT;
    const int n0 = (nt * BLK + tid) * VEC;

    for (int i = tid; i < CT * OT; i += BLK)
        wlds[i] = Wt[(size_t)(i / OT) * O + oBase + (i % OT)];
    __syncthreads();

    const float* s0 = src0 + (size_t)(nb / qdiv0) * CT * N + n0;

    float acc[OT][VEC];
#pragma unroll
    for (int ol = 0; ol < OT; ++ol)
#pragma unroll
        for (int j = 0; j < VEC; ++j) acc[ol][j] = 0.f;

    auto loadrow = [&](float (&x)[VEC], int c) {
        const float* p = s0 + (size_t)c * N;
        if constexpr (VEC == 4) {
            float4 t = *reinterpret_cast<const float4*>(p);
            x[0] = t.x; x[1] = t.y; x[2] = t.z; x[3] = t.w;
        } else if constexpr (VEC == 2) {
            float2 t = *reinterpret_cast<const float2*>(p);
            x[0] = t.x; x[1] = t.y;
        } else {
            x[0] = *p;
        }
    };
    auto comprow = [&](const float (&x)[VEC], int c) {
        if constexpr (OT >= 4) {
#pragma unroll
            for (int g = 0; g < OT / 4; ++g) {
                float4 wv = *reinterpret_cast<const float4*>(&wlds[c * OT + g * 4]);
                float ww[4] = {wv.x, wv.y, wv.z, wv.w};
#pragma unroll
                for (int r = 0; r < 4; ++r)
#pragma unroll
                    for (int j = 0; j < VEC; ++j)
                        acc[g * 4 + r][j] += ww[r] * x[j];
            }
        } else {
#pragma unroll
            for (int ol = 0; ol < OT; ++ol) {
                float w = wlds[c * OT + ol];
#pragma unroll
                for (int j = 0; j < VEC; ++j) acc[ol][j] += w * x[j];
            }
        }
    };
    auto loadg = [&](float (&buf)[4][VEC], int c) {
#pragma unroll
        for (int q = 0; q < 4; ++q) loadrow(buf[q], c + q);
    };
    auto compg = [&](const float (&buf)[4][VEC], int c) {
#pragma unroll
        for (int q = 0; q < 4; ++q) comprow(buf[q], c + q);
    };

    if constexpr (CT == 3) {
        float xs[3][VEC];
        loadrow(xs[0], 0); loadrow(xs[1], 1); loadrow(xs[2], 2);
        comprow(xs[0], 0); comprow(xs[1], 1); comprow(xs[2], 2);
    } else {
        static_assert(CT % 8 == 0 || CT % 8 == 4, "CT pipeline tail");
        float xa[4][VEC], xb[4][VEC];
        loadg(xa, 0); loadg(xb, 4);
        int c = 0;
#pragma unroll 1
        for (; c + 16 <= CT; c += 8) {
            compg(xa, c);     loadg(xa, c + 8);
            compg(xb, c + 4); loadg(xb, c + 12);
        }
        compg(xa, c);
        if constexpr (CT % 8 == 4) {
            loadg(xa, c + 8);
            compg(xb, c + 4);
            compg(xa, c + 8);
        } else {
            compg(xb, c + 4);
        }
    }

    const float* bp = USE_BASE ? (basep + ((size_t)(nb / qdivb) * O + oBase) * N + n0) : nullptr;
#pragma unroll
    for (int ol = 0; ol < OT; ++ol) {
        int o = oBase + ol;
        float addv[VEC];
        if constexpr (USE_BASE) {
            const float* p = bp + (size_t)ol * N;
            if constexpr (VEC == 4) {
                float4 t = *reinterpret_cast<const float4*>(p);
                addv[0] = t.x; addv[1] = t.y; addv[2] = t.z; addv[3] = t.w;
            } else if constexpr (VEC == 2) {
                float2 t = *reinterpret_cast<const float2*>(p);
                addv[0] = t.x; addv[1] = t.y;
            } else addv[0] = *p;
        } else {
            float sb = shb[o];
#pragma unroll
            for (int j = 0; j < VEC; ++j) addv[j] = sb;
        }
        float res[VEC];
#pragma unroll
        for (int j = 0; j < VEC; ++j) {
            float y = acc[ol][j] + addv[j];
            if constexpr (RELU) y = fmaxf(y, 0.f);
            res[j] = y;
        }
        float* op = outp + ((size_t)nb * O + o) * N + n0;
        if constexpr (VEC == 4) {
            float4 t; t.x = res[0]; t.y = res[1]; t.z = res[2]; t.w = res[3];
            *reinterpret_cast<float4*>(op) = t;
        } else if constexpr (VEC == 2) {
            float2 t; t.x = res[0]; t.y = res[1];
            *reinterpret_cast<float2*>(op) = t;
        } else {
            *op = res[0];
        }
    }
}

// ---------------- fused h6 + out: all 36 h6 channels in regs, dot, write 1 row
__global__ __launch_bounds__(64) void h6_out_kernel(
    const float* __restrict__ src,   // slotB (NB, 72, N)
    const float* __restrict__ Wt6,   // [72][36] scale-folded
    const float* __restrict__ shb6,  // [36]
    const float* __restrict__ wout,  // (36) raw out_w
    const float* __restrict__ bout,  // (1)
    float* __restrict__ outp, int N)
{
    __shared__ __align__(16) float wlds[72 * 36];
    __shared__ float ow[36], shs[36];
    const int tid = threadIdx.x;
    for (int i = tid; i < 72 * 36; i += 64) wlds[i] = Wt6[i];
    if (tid < 36) { ow[tid] = wout[tid]; shs[tid] = shb6[tid]; }
    __syncthreads();
    const int nb = blockIdx.z;
    const int n0 = (blockIdx.x * 64 + tid) * 2;
    const float* s0 = src + (size_t)nb * 72 * N + n0;

    float acc[36][2];
#pragma unroll
    for (int ol = 0; ol < 36; ++ol) { acc[ol][0] = 0.f; acc[ol][1] = 0.f; }

    auto loadrow = [&](float (&x)[2], int c) {
        float2 t = *reinterpret_cast<const float2*>(s0 + (size_t)c * N);
        x[0] = t.x; x[1] = t.y;
    };
    auto comprow = [&](const float (&x)[2], int c) {
#pragma unroll
        for (int g = 0; g < 9; ++g) {
            float4 wv = *reinterpret_cast<const float4*>(&wlds[c * 36 + g * 4]);
            float ww[4] = {wv.x, wv.y, wv.z, wv.w};
#pragma unroll
            for (int r = 0; r < 4; ++r) {
                acc[g * 4 + r][0] += ww[r] * x[0];
                acc[g * 4 + r][1] += ww[r] * x[1];
            }
        }
    };
    float xa[4][2], xb[4][2];
    auto loadg = [&](float (&buf)[4][2], int c) {
#pragma unroll
        for (int q = 0; q < 4; ++q) loadrow(buf[q], c + q);
    };
    auto compg = [&](const float (&buf)[4][2], int c) {
#pragma unroll
        for (int q = 0; q < 4; ++q) comprow(buf[q], c + q);
    };
    loadg(xa, 0); loadg(xb, 4);
    int c = 0;
#pragma unroll 1
    for (; c + 16 <= 72; c += 8) {
        compg(xa, c);     loadg(xa, c + 8);
        compg(xb, c + 4); loadg(xb, c + 12);
    }
    compg(xa, c); compg(xb, c + 4);

    float bo = bout[0];
    float r0 = bo, r1 = bo;
#pragma unroll
    for (int ol = 0; ol < 36; ++ol) {
        float y0 = fmaxf(acc[ol][0] + shs[ol], 0.f);
        float y1 = fmaxf(acc[ol][1] + shs[ol], 0.f);
        r0 += ow[ol] * y0; r1 += ow[ol] * y1;
    }
    float2 t; t.x = r0; t.y = r1;
    *reinterpret_cast<float2*>(outp + (size_t)nb * N + n0) = t;
}

extern "C" void kernel_launch(void* const* d_in, const int* in_sizes, int n_in,
                              void* d_out, int out_size, void* d_ws, size_t ws_size,
                              hipStream_t stream) {
    const int B = 2, Q = 16, N0 = 4096, N1 = 1024, N2 = 256;
    const int I1 = 144, I2 = 72, I3 = 36;
    const int NB = B * Q;  // 32

    const float* x     = (const float*)d_in[0];   // (B, 288, N2)
    const float* mask  = (const float*)d_in[1];   // (NB, 8, N2)
    const float* sa0f  = (const float*)d_in[2];   // (B, 3, N0)
    const float* sa1f  = (const float*)d_in[3];   // (B, 128, N1)
    const float* xyz0  = (const float*)d_in[4];   // (B, N0, 3)
    const float* xyz1  = (const float*)d_in[5];   // (B, N1, 3)
    const float* xyz2  = (const float*)d_in[6];   // (B, N2, 3)

    float* ws = (float*)d_ws;
    size_t off = 0;
    auto alloc = [&](size_t n) { size_t p = off; off += (n + 15) & ~(size_t)15; return p; };

    size_t f0b   = alloc((size_t)B * I2 * N0);
    size_t f1b   = alloc((size_t)B * I1 * N1);
    size_t wgt1  = alloc((size_t)B * N1 * 3);
    size_t wgt2  = alloc((size_t)B * N0 * 3);
    size_t idx1  = alloc((size_t)B * N1 * 3);
    size_t idx2  = alloc((size_t)B * N0 * 3);
    size_t slotA = alloc((size_t)NB * I2 * N0);   // h1 / interp1 / interp2
    size_t slotB = alloc((size_t)NB * I2 * N0);   // h2 / h3 / h5
    size_t slotC = alloc((size_t)NB * I2 * N1);   // h4
    size_t base1 = alloc((size_t)B * 296 * N2);
    size_t base3 = alloc((size_t)B * I1 * N1);
    size_t base5 = alloc((size_t)B * I2 * N0);
    size_t wt1 = alloc(296 * 296), sb1 = alloc(296);
    size_t wt2 = alloc(296 * 144), sb2 = alloc(144);
    size_t wt3 = alloc(288 * 144), sb3 = alloc(144);
    size_t wt4 = alloc(144 * 72),  sb4 = alloc(72);
    size_t wt5 = alloc(144 * 72),  sb5 = alloc(72);
    size_t wt6 = alloc(72 * 36),   sb6 = alloc(36);
    size_t wa1 = alloc(3 * 72),    sa1b = alloc(72);
    size_t wa2 = alloc(128 * 144), sa2b = alloc(144);
    (void)ws_size; (void)in_sizes; (void)n_in;

    auto din = [&](int i) { return (const float*)d_in[i]; };

    PrepArgs pa;
    pa.l[0] = { din(7),  din(8),  din(9),  ws + wt1, ws + sb1, 296, 296 };
    pa.l[1] = { din(10), din(11), din(12), ws + wt2, ws + sb2, 144, 296 };
    pa.l[2] = { din(17), din(18), din(19), ws + wt3, ws + sb3, 144, 288 };
    pa.l[3] = { din(20), din(21), din(22), ws + wt4, ws + sb4, 72, 144 };
    pa.l[4] = { din(23), din(24), din(25), ws + wt5, ws + sb5, 72, 144 };
    pa.l[5] = { din(26), din(27), din(28), ws + wt6, ws + sb6, 36, 72 };
    pa.l[6] = { din(13), din(14), nullptr, ws + wa1, ws + sa1b, 72, 3 };
    pa.l[7] = { din(15), din(16), nullptr, ws + wa2, ws + sa2b, 144, 128 };
    prep_kernel<<<dim3(16, 8), 256, 0, stream>>>(pa);

    // three_nn (per-b)
    three_nn_par_kernel<<<dim3(N1 / 32, B), dim3(512), 0, stream>>>(
        xyz1, xyz2, N1, N2, (int*)(ws + idx1), ws + wgt1);
    three_nn_par_kernel<<<dim3(N0 / 32, B), dim3(512), 0, stream>>>(
        xyz0, xyz1, N0, N1, (int*)(ws + idx2), ws + wgt2);

    // adapters (per-b)
    conv_tpl<64, 3, 72, 8, 4, false, false, false><<<dim3(16, 9, B), 64, 0, stream>>>(
        sa0f, 1, ws + wa1, ws + sa1b, nullptr, 1, ws + f0b, N0, 0, 0);
    conv_tpl<64, 128, 144, 8, 4, false, false, false><<<dim3(4, 18, B), 64, 0, stream>>>(
        sa1f, 1, ws + wa2, ws + sa2b, nullptr, 1, ws + f1b, N1, 0, 0);

    // base1 = W1[:, :288] @ x + shb1   (per-b)
    conv_tpl<64, 288, 296, 8, 4, false, false, false><<<dim3(1, 37, B), 64, 0, stream>>>(
        x, 1, ws + wt1, ws + sb1, nullptr, 1, ws + base1, N2, 0, 0);
    // h1 = ReLU(W1[:, 288:] @ mask + base1)   (per-nb, 1184 blocks)
    conv_tpl<64, 8, 296, 8, 4, true, true, true><<<dim3(1184), 64, 0, stream>>>(
        mask, 1, ws + wt1 + 288 * 296, ws + sb1, ws + base1, Q, ws + slotA, N2, 1, 37);

    // h2 : (NB, 144, 256)  [576 blocks]
    conv_tpl<64, 296, 144, 8, 4, true, false, true><<<dim3(576), 64, 0, stream>>>(
        ws + slotA, 1, ws + wt2, ws + sb2, nullptr, 1, ws + slotB, N2, 1, 18);

    // interp1: h2 (Ns=256) -> (NB, 144, 1024)
    interp_kernel<<<dim3(N1 / 256, NB), 256, 0, stream>>>(
        ws + slotB, (const int*)(ws + idx1), ws + wgt1, ws + slotA, I1, N2, N1, Q);

    // base3 = W3[:, 144:] @ f1 + shb3   (per-b)
    conv_tpl<64, 144, 144, 8, 4, false, false, false><<<dim3(4, 18, B), 64, 0, stream>>>(
        ws + f1b, 1, ws + wt3 + 144 * 144, ws + sb3, nullptr, 1, ws + base3, N1, 0, 0);
    // h3 = ReLU(W3[:, :144] @ interp1 + base3)   [2304 blocks]
    conv_tpl<64, 144, 144, 8, 4, true, true, true><<<dim3(2304), 64, 0, stream>>>(
        ws + slotA, 1, ws + wt3, ws + sb3, ws + base3, Q, ws + slotB, N1, 4, 18);

    // h4 -> slotC   [1152 blocks]
    conv_tpl<64, 144, 72, 8, 4, true, false, true><<<dim3(1152), 64, 0, stream>>>(
        ws + slotB, 1, ws + wt4, ws + sb4, nullptr, 1, ws + slotC, N1, 4, 9);

    // interp2: h4 (Ns=1024) -> (NB, 72, 4096)
    interp_kernel<<<dim3(N0 / 256, NB), 256, 0, stream>>>(
        ws + slotC, (const int*)(ws + idx2), ws + wgt2, ws + slotA, I2, N1, N0, Q);

    // base5 = W5[:, 72:] @ f0 + shb5   (per-b)
    conv_tpl<64, 72, 72, 8, 4, false, false, false><<<dim3(16, 9, B), 64, 0, stream>>>(
        ws + f0b, 1, ws + wt5 + 72 * 72, ws + sb5, nullptr, 1, ws + base5, N0, 0, 0);
    // h5 = ReLU(W5[:, :72] @ interp2 + base5)   [4608 blocks]
    conv_tpl<64, 72, 72, 8, 4, true, true, true><<<dim3(4608), 64, 0, stream>>>(
        ws + slotA, 1, ws + wt5, ws + sb5, ws + base5, Q, ws + slotB, N0, 16, 9);

    // fused h6 + out -> d_out   [1024 blocks]
    h6_out_kernel<<<dim3(32, 1, NB), 64, 0, stream>>>(
        ws + slotB, ws + wt6, ws + sb6, din(29), din(30), (float*)d_out, N0);
}

// Round 9
// 242.794 us; speedup vs baseline: 1.3836x; 1.2163x over previous
//
#include <hip/hip_runtime.h>

#define EPS_BN 1e-5f

// ---------------- merged three_nn: blocks [0,32)=task1(N1<-N2), [32,160)=task2(N0<-N1)
__global__ __launch_bounds__(512) void three_nn2_kernel(
    const float* __restrict__ xyz0, const float* __restrict__ xyz1,
    const float* __restrict__ xyz2,
    int* __restrict__ idx1, float* __restrict__ wgt1,
    int* __restrict__ idx2, float* __restrict__ wgt2)
{
    const int NSEG = 16;
    __shared__ float kl[3 * 1024];
    __shared__ float sd[NSEG][32][3];
    __shared__ int   si[NSEG][32][3];
    const int b = blockIdx.y;
    const float* unknown; const float* known;
    int Nu, Nk, blk; int* idx; float* wgt;
    if (blockIdx.x < 32) {
        unknown = xyz1; known = xyz2; Nu = 1024; Nk = 256;
        blk = blockIdx.x; idx = idx1; wgt = wgt1;
    } else {
        unknown = xyz0; known = xyz1; Nu = 4096; Nk = 1024;
        blk = blockIdx.x - 32; idx = idx2; wgt = wgt2;
    }
    for (int i = threadIdx.x; i < Nk * 3; i += 512) kl[i] = known[(size_t)b * Nk * 3 + i];
    __syncthreads();
    const int u   = threadIdx.x & 31;
    const int seg = threadIdx.x >> 5;
    const int n   = blk * 32 + u;
    const float* up = unknown + ((size_t)b * Nu + n) * 3;
    const float ux = up[0], uy = up[1], uz = up[2];
    float d0 = 1e30f, d1 = 1e30f, d2 = 1e30f;
    int i0 = 0, i1 = 0, i2 = 0;
    const int klo = seg * (Nk / NSEG), khi = klo + Nk / NSEG;
    for (int k = klo; k < khi; ++k) {
        float dx = __fsub_rn(ux, kl[3 * k + 0]);
        float dy = __fsub_rn(uy, kl[3 * k + 1]);
        float dz = __fsub_rn(uz, kl[3 * k + 2]);
        float d = __fadd_rn(__fadd_rn(__fmul_rn(dx, dx), __fmul_rn(dy, dy)), __fmul_rn(dz, dz));
        if (d < d0)      { d2 = d1; i2 = i1; d1 = d0; i1 = i0; d0 = d; i0 = k; }
        else if (d < d1) { d2 = d1; i2 = i1; d1 = d;  i1 = k; }
        else if (d < d2) { d2 = d;  i2 = k; }
    }
    sd[seg][u][0] = d0; sd[seg][u][1] = d1; sd[seg][u][2] = d2;
    si[seg][u][0] = i0; si[seg][u][1] = i1; si[seg][u][2] = i2;
    __syncthreads();
    if (threadIdx.x < 32) {
        float m0 = 1e30f, m1 = 1e30f, m2 = 1e30f;
        int j0 = 0, j1 = 0, j2 = 0;
        for (int s = 0; s < NSEG; ++s)
            for (int c = 0; c < 3; ++c) {
                float d = sd[s][u][c];
                int ii = si[s][u][c];
                if (d < m0)      { m2 = m1; j2 = j1; m1 = m0; j1 = j0; m0 = d; j0 = ii; }
                else if (d < m1) { m2 = m1; j2 = j1; m1 = d;  j1 = ii; }
                else if (d < m2) { m2 = d;  j2 = ii; }
            }
        float w0 = 1.f / (m0 + 1e-8f), w1 = 1.f / (m1 + 1e-8f), w2 = 1.f / (m2 + 1e-8f);
        float s = w0 + w1 + w2;
        size_t base = ((size_t)b * Nu + n) * 3;
        idx[base + 0] = j0; idx[base + 1] = j1; idx[base + 2] = j2;
        wgt[base + 0] = w0 / s; wgt[base + 1] = w1 / s; wgt[base + 2] = w2 / s;
    }
}

// ---------------- interp: LDS-staged gather, 8 rows/chunk ----------------
template <int C, int NS>
__global__ __launch_bounds__(256) void interp_lds_kernel(
    const float* __restrict__ feat,                              // (NB, C, NS)
    const int* __restrict__ idx, const float* __restrict__ wgt,  // (B, Nu, 3)
    float* __restrict__ out, int Nu, int Q)                      // (NB, C, Nu)
{
    __shared__ __align__(16) float rows[8 * NS];
    const int tid = threadIdx.x;
    const int n = blockIdx.x * 256 + tid;
    const int nb = blockIdx.y;
    const int b = nb / Q;
    size_t nnb = ((size_t)b * Nu + n) * 3;
    const int j0 = idx[nnb], j1 = idx[nnb + 1], j2 = idx[nnb + 2];
    const float w0 = wgt[nnb], w1 = wgt[nnb + 1], w2 = wgt[nnb + 2];
    const float* fbase = feat + (size_t)nb * C * NS;
    float* obase = out + (size_t)nb * C * Nu + n;
    for (int cc = 0; cc < C; cc += 8) {
        __syncthreads();
        const float4* src = reinterpret_cast<const float4*>(fbase + (size_t)cc * NS);
        float4* dst = reinterpret_cast<float4*>(rows);
        for (int i = tid; i < 2 * NS; i += 256) dst[i] = src[i];
        __syncthreads();
#pragma unroll
        for (int r = 0; r < 8; ++r) {
            const float* rp = rows + r * NS;
            obase[(size_t)(cc + r) * Nu] = w0 * rp[j0] + w1 * rp[j1] + w2 * rp[j2];
        }
    }
}

// ---------------- prep (transpose+fold BN) + composite adapters ----------------
struct LayerDesc {
    const float* W; const float* b; const float* bn;
    float* wt; float* shb; int O; int C;
};
struct PCArgs {
    LayerDesc l[6];
    const float* a2w; const float* a2b; const float* w3; const float* b3; const float* bn3;
    float* w3c; float* sh3;
    const float* a1w; const float* a1b; const float* w5; const float* b5; const float* bn5;
    float* w5c; float* sh5;
};

__global__ __launch_bounds__(256) void prep_compose_kernel(PCArgs a) {
    const int bx = blockIdx.x, tid = threadIdx.x;
    if (bx < 96) {
        LayerDesc d = a.l[bx / 16];
        int sub = bx % 16;
        int total = d.O * d.C;
        for (int i = sub * 256 + tid; i < total; i += 16 * 256) {
            int c = i / d.O, o = i - (i / d.O) * d.O;
            float sc = 1.f;
            if (d.bn) { float g = d.bn[o], v = d.bn[3 * d.O + o]; sc = g * rsqrtf(v + EPS_BN); }
            d.wt[i] = d.W[(size_t)o * d.C + c] * sc;
        }
        for (int o = sub * 256 + tid; o < d.O; o += 16 * 256) {
            float sc = 1.f, sh = 0.f;
            if (d.bn) {
                float g = d.bn[o], be = d.bn[d.O + o], m = d.bn[2 * d.O + o], v = d.bn[3 * d.O + o];
                sc = g * rsqrtf(v + EPS_BN); sh = be - m * sc;
            }
            d.shb[o] = d.b[o] * sc + sh;
        }
    } else if (bx < 169) {
        // composite for fp1 layer1's f1 half: W3c[k][o] = sum_c A2[c][k]*W3[o][144+c]*sc3[o]
        int e = (bx - 96) * 256 + tid;
        if (e < 128 * 144) {
            int k = e / 144, o = e - (e / 144) * 144;
            float sc = a.bn3[o] * rsqrtf(a.bn3[3 * 144 + o] + EPS_BN);
            float s = 0.f;
            for (int c = 0; c < 144; ++c)
                s += a.a2w[c * 128 + k] * a.w3[(size_t)o * 288 + 144 + c];
            a.w3c[k * 144 + o] = s * sc;
        } else if (e < 128 * 144 + 144) {
            int o = e - 128 * 144;
            float g = a.bn3[o], be = a.bn3[144 + o], m = a.bn3[2 * 144 + o], v = a.bn3[3 * 144 + o];
            float sc = g * rsqrtf(v + EPS_BN);
            float s = 0.f;
            for (int c = 0; c < 144; ++c) s += a.w3[(size_t)o * 288 + 144 + c] * a.a2b[c];
            a.sh3[o] = (s + a.b3[o] - m) * sc + be;
        }
    } else {
        // composite for fp2 layer1's f0 half: W5c[k][o] = sum_c A1[c][k]*W5[o][72+c]*sc5[o]
        int e = (bx - 169) * 256 + tid;
        if (e < 3 * 72) {
            int k = e / 72, o = e - (e / 72) * 72;
            float sc = a.bn5[o] * rsqrtf(a.bn5[3 * 72 + o] + EPS_BN);
            float s = 0.f;
            for (int c = 0; c < 72; ++c)
                s += a.a1w[c * 3 + k] * a.w5[(size_t)o * 144 + 72 + c];
            a.w5c[k * 72 + o] = s * sc;
        } else if (e < 3 * 72 + 72) {
            int o = e - 3 * 72;
            float g = a.bn5[o], be = a.bn5[72 + o], m = a.bn5[2 * 72 + o], v = a.bn5[3 * 72 + o];
            float sc = g * rsqrtf(v + EPS_BN);
            float s = 0.f;
            for (int c = 0; c < 72; ++c) s += a.w5[(size_t)o * 144 + 72 + c] * a.a1b[c];
            a.sh5[o] = (s + a.b5[o] - m) * sc + be;
        }
    }
}

// ---------------- conv body (r8-proven structure) ----------------
template <int BLK, int CT, int O, int OT, int VEC, bool RELU, bool USE_BASE>
__device__ __forceinline__ void conv_body(
    int nt, int ot, int nb, int tid,
    const float* __restrict__ src0, int qdiv0,
    const float* __restrict__ Wt, const float* __restrict__ shb,
    const float* __restrict__ basep, int qdivb,
    float* __restrict__ outp, int N, float* wlds)
{
    const int oBase = ot * OT;
    const int n0 = (nt * BLK + tid) * VEC;

    for (int i = tid; i < CT * OT; i += BLK)
        wlds[i] = Wt[(size_t)(i / OT) * O + oBase + (i % OT)];
    __syncthreads();

    const float* s0 = src0 + (size_t)(nb / qdiv0) * CT * N + n0;

    float acc[OT][VEC];
#pragma unroll
    for (int ol = 0; ol < OT; ++ol)
#pragma unroll
        for (int j = 0; j < VEC; ++j) acc[ol][j] = 0.f;

    auto loadrow = [&](float (&x)[VEC], int c) {
        const float* p = s0 + (size_t)c * N;
        if constexpr (VEC == 4) {
            float4 t = *reinterpret_cast<const float4*>(p);
            x[0] = t.x; x[1] = t.y; x[2] = t.z; x[3] = t.w;
        } else if constexpr (VEC == 2) {
            float2 t = *reinterpret_cast<const float2*>(p);
            x[0] = t.x; x[1] = t.y;
        } else {
            x[0] = *p;
        }
    };
    auto comprow = [&](const float (&x)[VEC], int c) {
        if constexpr (OT >= 4) {
#pragma unroll
            for (int g = 0; g < OT / 4; ++g) {
                float4 wv = *reinterpret_cast<const float4*>(&wlds[c * OT + g * 4]);
                float ww[4] = {wv.x, wv.y, wv.z, wv.w};
#pragma unroll
                for (int r = 0; r < 4; ++r)
#pragma unroll
                    for (int j = 0; j < VEC; ++j)
                        acc[g * 4 + r][j] += ww[r] * x[j];
            }
        } else {
#pragma unroll
            for (int ol = 0; ol < OT; ++ol) {
                float w = wlds[c * OT + ol];
#pragma unroll
                for (int j = 0; j < VEC; ++j) acc[ol][j] += w * x[j];
            }
        }
    };
    auto loadg = [&](float (&buf)[4][VEC], int c) {
#pragma unroll
        for (int q = 0; q < 4; ++q) loadrow(buf[q], c + q);
    };
    auto compg = [&](const float (&buf)[4][VEC], int c) {
#pragma unroll
        for (int q = 0; q < 4; ++q) comprow(buf[q], c + q);
    };

    if constexpr (CT == 3) {
        float xs[3][VEC];
        loadrow(xs[0], 0); loadrow(xs[1], 1); loadrow(xs[2], 2);
        comprow(xs[0], 0); comprow(xs[1], 1); comprow(xs[2], 2);
    } else {
        static_assert(CT % 8 == 0 || CT % 8 == 4, "CT pipeline tail");
        float xa[4][VEC], xb[4][VEC];
        loadg(xa, 0); loadg(xb, 4);
        int c = 0;
#pragma unroll 1
        for (; c + 16 <= CT; c += 8) {
            compg(xa, c);     loadg(xa, c + 8);
            compg(xb, c + 4); loadg(xb, c + 12);
        }
        compg(xa, c);
        if constexpr (CT % 8 == 4) {
            loadg(xa, c + 8);
            compg(xb, c + 4);
            compg(xa, c + 8);
        } else {
            compg(xb, c + 4);
        }
    }

    const float* bp = USE_BASE ? (basep + ((size_t)(nb / qdivb) * O + oBase) * N + n0) : nullptr;
#pragma unroll
    for (int ol = 0; ol < OT; ++ol) {
        int o = oBase + ol;
        float addv[VEC];
        if constexpr (USE_BASE) {
            const float* p = bp + (size_t)ol * N;
            if constexpr (VEC == 4) {
                float4 t = *reinterpret_cast<const float4*>(p);
                addv[0] = t.x; addv[1] = t.y; addv[2] = t.z; addv[3] = t.w;
            } else if constexpr (VEC == 2) {
                float2 t = *reinterpret_cast<const float2*>(p);
                addv[0] = t.x; addv[1] = t.y;
            } else addv[0] = *p;
        } else {
            float sb = shb[o];
#pragma unroll
            for (int j = 0; j < VEC; ++j) addv[j] = sb;
        }
        float res[VEC];
#pragma unroll
        for (int j = 0; j < VEC; ++j) {
            float y = acc[ol][j] + addv[j];
            if constexpr (RELU) y = fmaxf(y, 0.f);
            res[j] = y;
        }
        float* op = outp + ((size_t)nb * O + o) * N + n0;
        if constexpr (VEC == 4) {
            float4 t; t.x = res[0]; t.y = res[1]; t.z = res[2]; t.w = res[3];
            *reinterpret_cast<float4*>(op) = t;
        } else if constexpr (VEC == 2) {
            float2 t; t.x = res[0]; t.y = res[1];
            *reinterpret_cast<float2*>(op) = t;
        } else {
            *op = res[0];
        }
    }
}

// main convs: flat grid, XCD-bijective swizzle, o-tile innermost
template <int BLK, int CT, int O, int OT, int VEC, bool RELU, bool USE_BASE>
__global__ __launch_bounds__(BLK) void conv_swz(
    const float* __restrict__ src0, int qdiv0,
    const float* __restrict__ Wt, const float* __restrict__ shb,
    const float* __restrict__ basep, int qdivb,
    float* __restrict__ outp, int N, int GX, int GY)
{
    __shared__ __align__(16) float wlds[CT * OT];
    int f = blockIdx.x;
    int J = gridDim.x >> 3;
    int j = (f & 7) * J + (f >> 3);
    int ot = j % GY; int r = j / GY;
    int nt = r % GX; int nb = r / GX;
    conv_body<BLK, CT, O, OT, VEC, RELU, USE_BASE>(
        nt, ot, nb, threadIdx.x, src0, qdiv0, Wt, shb, basep, qdivb, outp, N, wlds);
}

// merged per-b base GEMMs: [0,74)=base1, [74,218)=base3, [218,506)=base5
__global__ __launch_bounds__(64) void bases_kernel(
    const float* __restrict__ x, const float* __restrict__ sa1f, const float* __restrict__ sa0f,
    const float* __restrict__ wt1, const float* __restrict__ sb1,
    const float* __restrict__ w3c, const float* __restrict__ sh3,
    const float* __restrict__ w5c, const float* __restrict__ sh5,
    float* __restrict__ base1, float* __restrict__ base3, float* __restrict__ base5)
{
    __shared__ __align__(16) float wlds[288 * 8];
    const int bx = blockIdx.x, tid = threadIdx.x;
    if (bx < 74) {
        int ot = bx % 37, nb = bx / 37;
        conv_body<64, 288, 296, 8, 4, false, false>(0, ot, nb, tid, x, 1, wt1, sb1, nullptr, 1, base1, 256, wlds);
    } else if (bx < 218) {
        int lb = bx - 74;
        int nt = lb % 4, ot = (lb / 4) % 18, nb = lb / 72;
        conv_body<64, 128, 144, 8, 4, false, false>(nt, ot, nb, tid, sa1f, 1, w3c, sh3, nullptr, 1, base3, 1024, wlds);
    } else {
        int lb = bx - 218;
        int nt = lb % 16, ot = (lb / 16) % 9, nb = lb / 144;
        conv_body<64, 3, 72, 8, 4, false, false>(nt, ot, nb, tid, sa0f, 1, w5c, sh5, nullptr, 1, base5, 4096, wlds);
    }
}

// ---------------- fused h6 + out ----------------
__global__ __launch_bounds__(64) void h6_out_kernel(
    const float* __restrict__ src,   // (NB, 72, N)
    const float* __restrict__ Wt6,   // [72][36] scale-folded
    const float* __restrict__ shb6,  // [36]
    const float* __restrict__ wout, const float* __restrict__ bout,
    float* __restrict__ outp, int N)
{
    __shared__ __align__(16) float wlds[72 * 36];
    __shared__ float ow[36], shs[36];
    const int tid = threadIdx.x;
    for (int i = tid; i < 72 * 36; i += 64) wlds[i] = Wt6[i];
    if (tid < 36) { ow[tid] = wout[tid]; shs[tid] = shb6[tid]; }
    __syncthreads();
    const int nb = blockIdx.z;
    const int n0 = (blockIdx.x * 64 + tid) * 2;
    const float* s0 = src + (size_t)nb * 72 * N + n0;

    float acc[36][2];
#pragma unroll
    for (int ol = 0; ol < 36; ++ol) { acc[ol][0] = 0.f; acc[ol][1] = 0.f; }

    auto loadrow = [&](float (&x)[2], int c) {
        float2 t = *reinterpret_cast<const float2*>(s0 + (size_t)c * N);
        x[0] = t.x; x[1] = t.y;
    };
    auto comprow = [&](const float (&x)[2], int c) {
#pragma unroll
        for (int g = 0; g < 9; ++g) {
            float4 wv = *reinterpret_cast<const float4*>(&wlds[c * 36 + g * 4]);
            float ww[4] = {wv.x, wv.y, wv.z, wv.w};
#pragma unroll
            for (int r = 0; r < 4; ++r) {
                acc[g * 4 + r][0] += ww[r] * x[0];
                acc[g * 4 + r][1] += ww[r] * x[1];
            }
        }
    };
    float xa[4][2], xb[4][2];
    auto loadg = [&](float (&buf)[4][2], int c) {
#pragma unroll
        for (int q = 0; q < 4; ++q) loadrow(buf[q], c + q);
    };
    auto compg = [&](const float (&buf)[4][2], int c) {
#pragma unroll
        for (int q = 0; q < 4; ++q) comprow(buf[q], c + q);
    };
    loadg(xa, 0); loadg(xb, 4);
    int c = 0;
#pragma unroll 1
    for (; c + 16 <= 72; c += 8) {
        compg(xa, c);     loadg(xa, c + 8);
        compg(xb, c + 4); loadg(xb, c + 12);
    }
    compg(xa, c); compg(xb, c + 4);

    float bo = bout[0];
    float r0 = bo, r1 = bo;
#pragma unroll
    for (int ol = 0; ol < 36; ++ol) {
        float y0 = fmaxf(acc[ol][0] + shs[ol], 0.f);
        float y1 = fmaxf(acc[ol][1] + shs[ol], 0.f);
        r0 += ow[ol] * y0; r1 += ow[ol] * y1;
    }
    float2 t; t.x = r0; t.y = r1;
    *reinterpret_cast<float2*>(outp + (size_t)nb * N + n0) = t;
}

extern "C" void kernel_launch(void* const* d_in, const int* in_sizes, int n_in,
                              void* d_out, int out_size, void* d_ws, size_t ws_size,
                              hipStream_t stream) {
    const int B = 2, Q = 16, N0 = 4096, N1 = 1024, N2 = 256;
    const int I1 = 144, I2 = 72;
    const int NB = B * Q;  // 32

    const float* x     = (const float*)d_in[0];
    const float* mask  = (const float*)d_in[1];
    const float* sa0f  = (const float*)d_in[2];
    const float* sa1f  = (const float*)d_in[3];
    const float* xyz0  = (const float*)d_in[4];
    const float* xyz1  = (const float*)d_in[5];
    const float* xyz2  = (const float*)d_in[6];

    float* ws = (float*)d_ws;
    size_t off = 0;
    auto alloc = [&](size_t n) { size_t p = off; off += (n + 15) & ~(size_t)15; return p; };

    size_t wgt1  = alloc((size_t)B * N1 * 3);
    size_t wgt2  = alloc((size_t)B * N0 * 3);
    size_t idx1  = alloc((size_t)B * N1 * 3);
    size_t idx2  = alloc((size_t)B * N0 * 3);
    size_t slotA = alloc((size_t)NB * I2 * N0);   // h1 / interp1 / interp2
    size_t slotB = alloc((size_t)NB * I2 * N0);   // h2 / h3 / h5
    size_t slotC = alloc((size_t)NB * I2 * N1);   // h4
    size_t base1 = alloc((size_t)B * 296 * N2);
    size_t base3 = alloc((size_t)B * I1 * N1);
    size_t base5 = alloc((size_t)B * I2 * N0);
    size_t wt1 = alloc(296 * 296), sb1 = alloc(296);
    size_t wt2 = alloc(296 * 144), sb2 = alloc(144);
    size_t wt3 = alloc(288 * 144), sb3 = alloc(144);
    size_t wt4 = alloc(144 * 72),  sb4 = alloc(72);
    size_t wt5 = alloc(144 * 72),  sb5 = alloc(72);
    size_t wt6 = alloc(72 * 36),   sb6 = alloc(36);
    size_t w3c = alloc(128 * 144), sh3 = alloc(144);
    size_t w5c = alloc(3 * 72),    sh5 = alloc(72);
    (void)ws_size; (void)in_sizes; (void)n_in;

    auto din = [&](int i) { return (const float*)d_in[i]; };

    PCArgs pa;
    pa.l[0] = { din(7),  din(8),  din(9),  ws + wt1, ws + sb1, 296, 296 };
    pa.l[1] = { din(10), din(11), din(12), ws + wt2, ws + sb2, 144, 296 };
    pa.l[2] = { din(17), din(18), din(19), ws + wt3, ws + sb3, 144, 288 };
    pa.l[3] = { din(20), din(21), din(22), ws + wt4, ws + sb4, 72, 144 };
    pa.l[4] = { din(23), din(24), din(25), ws + wt5, ws + sb5, 72, 144 };
    pa.l[5] = { din(26), din(27), din(28), ws + wt6, ws + sb6, 36, 72 };
    pa.a2w = din(15); pa.a2b = din(16); pa.w3 = din(17); pa.b3 = din(18); pa.bn3 = din(19);
    pa.w3c = ws + w3c; pa.sh3 = ws + sh3;
    pa.a1w = din(13); pa.a1b = din(14); pa.w5 = din(23); pa.b5 = din(24); pa.bn5 = din(25);
    pa.w5c = ws + w5c; pa.sh5 = ws + sh5;
    prep_compose_kernel<<<dim3(171), 256, 0, stream>>>(pa);

    // merged three_nn
    three_nn2_kernel<<<dim3(160, B), 512, 0, stream>>>(
        xyz0, xyz1, xyz2, (int*)(ws + idx1), ws + wgt1, (int*)(ws + idx2), ws + wgt2);

    // merged per-b bases (base1 | base3 | base5)
    bases_kernel<<<dim3(506), 64, 0, stream>>>(
        x, sa1f, sa0f, ws + wt1, ws + sb1, ws + w3c, ws + sh3, ws + w5c, ws + sh5,
        ws + base1, ws + base3, ws + base5);

    // h1 = ReLU(W1[:,288:] @ mask + base1)   [1184 blocks]
    conv_swz<64, 8, 296, 8, 4, true, true><<<dim3(1184), 64, 0, stream>>>(
        mask, 1, ws + wt1 + 288 * 296, ws + sb1, ws + base1, Q, ws + slotA, N2, 1, 37);

    // h2   [576 blocks]
    conv_swz<64, 296, 144, 8, 4, true, false><<<dim3(576), 64, 0, stream>>>(
        ws + slotA, 1, ws + wt2, ws + sb2, nullptr, 1, ws + slotB, N2, 1, 18);

    // interp1: h2 (NS=256) -> (NB, 144, 1024)
    interp_lds_kernel<144, 256><<<dim3(N1 / 256, NB), 256, 0, stream>>>(
        ws + slotB, (const int*)(ws + idx1), ws + wgt1, ws + slotA, N1, Q);

    // h3 = ReLU(W3[:, :144] @ interp1 + base3)   [2304 blocks]
    conv_swz<64, 144, 144, 8, 4, true, true><<<dim3(2304), 64, 0, stream>>>(
        ws + slotA, 1, ws + wt3, ws + sb3, ws + base3, Q, ws + slotB, N1, 4, 18);

    // h4   [1152 blocks]
    conv_swz<64, 144, 72, 8, 4, true, false><<<dim3(1152), 64, 0, stream>>>(
        ws + slotB, 1, ws + wt4, ws + sb4, nullptr, 1, ws + slotC, N1, 4, 9);

    // interp2: h4 (NS=1024) -> (NB, 72, 4096)
    interp_lds_kernel<72, 1024><<<dim3(N0 / 256, NB), 256, 0, stream>>>(
        ws + slotC, (const int*)(ws + idx2), ws + wgt2, ws + slotA, N0, Q);

    // h5 = ReLU(W5[:, :72] @ interp2 + base5)   [4608 blocks]
    conv_swz<64, 72, 72, 8, 4, true, true><<<dim3(4608), 64, 0, stream>>>(
        ws + slotA, 1, ws + wt5, ws + sb5, ws + base5, Q, ws + slotB, N0, 16, 9);

    // fused h6 + out -> d_out   [1024 blocks]
    h6_out_kernel<<<dim3(32, 1, NB), 64, 0, stream>>>(
        ws + slotB, ws + wt6, ws + sb6, din(29), din(30), (float*)d_out, N0);
}

// Round 10
// 214.670 us; speedup vs baseline: 1.5649x; 1.1310x over previous
//
#include <hip/hip_runtime.h>

#define EPS_BN 1e-5f

// ---------------- merged three_nn: blocks [0,32)=task1(N1<-N2), [32,160)=task2(N0<-N1)
__global__ __launch_bounds__(512) void three_nn2_kernel(
    const float* __restrict__ xyz0, const float* __restrict__ xyz1,
    const float* __restrict__ xyz2,
    int* __restrict__ idx1, float* __restrict__ wgt1,
    int* __restrict__ idx2, float* __restrict__ wgt2)
{
    const int NSEG = 16;
    __shared__ float kl[3 * 1024];
    __shared__ float sd[NSEG][32][3];
    __shared__ int   si[NSEG][32][3];
    const int b = blockIdx.y;
    const float* unknown; const float* known;
    int Nu, Nk, blk; int* idx; float* wgt;
    if (blockIdx.x < 32) {
        unknown = xyz1; known = xyz2; Nu = 1024; Nk = 256;
        blk = blockIdx.x; idx = idx1; wgt = wgt1;
    } else {
        unknown = xyz0; known = xyz1; Nu = 4096; Nk = 1024;
        blk = blockIdx.x - 32; idx = idx2; wgt = wgt2;
    }
    for (int i = threadIdx.x; i < Nk * 3; i += 512) kl[i] = known[(size_t)b * Nk * 3 + i];
    __syncthreads();
    const int u   = threadIdx.x & 31;
    const int seg = threadIdx.x >> 5;
    const int n   = blk * 32 + u;
    const float* up = unknown + ((size_t)b * Nu + n) * 3;
    const float ux = up[0], uy = up[1], uz = up[2];
    float d0 = 1e30f, d1 = 1e30f, d2 = 1e30f;
    int i0 = 0, i1 = 0, i2 = 0;
    const int klo = seg * (Nk / NSEG), khi = klo + Nk / NSEG;
    for (int k = klo; k < khi; ++k) {
        float dx = __fsub_rn(ux, kl[3 * k + 0]);
        float dy = __fsub_rn(uy, kl[3 * k + 1]);
        float dz = __fsub_rn(uz, kl[3 * k + 2]);
        float d = __fadd_rn(__fadd_rn(__fmul_rn(dx, dx), __fmul_rn(dy, dy)), __fmul_rn(dz, dz));
        if (d < d0)      { d2 = d1; i2 = i1; d1 = d0; i1 = i0; d0 = d; i0 = k; }
        else if (d < d1) { d2 = d1; i2 = i1; d1 = d;  i1 = k; }
        else if (d < d2) { d2 = d;  i2 = k; }
    }
    sd[seg][u][0] = d0; sd[seg][u][1] = d1; sd[seg][u][2] = d2;
    si[seg][u][0] = i0; si[seg][u][1] = i1; si[seg][u][2] = i2;
    __syncthreads();
    if (threadIdx.x < 32) {
        float m0 = 1e30f, m1 = 1e30f, m2 = 1e30f;
        int j0 = 0, j1 = 0, j2 = 0;
        for (int s = 0; s < NSEG; ++s)
            for (int c = 0; c < 3; ++c) {
                float d = sd[s][u][c];
                int ii = si[s][u][c];
                if (d < m0)      { m2 = m1; j2 = j1; m1 = m0; j1 = j0; m0 = d; j0 = ii; }
                else if (d < m1) { m2 = m1; j2 = j1; m1 = d;  j1 = ii; }
                else if (d < m2) { m2 = d;  j2 = ii; }
            }
        float w0 = 1.f / (m0 + 1e-8f), w1 = 1.f / (m1 + 1e-8f), w2 = 1.f / (m2 + 1e-8f);
        float s = w0 + w1 + w2;
        size_t base = ((size_t)b * Nu + n) * 3;
        idx[base + 0] = j0; idx[base + 1] = j1; idx[base + 2] = j2;
        wgt[base + 0] = w0 / s; wgt[base + 1] = w1 / s; wgt[base + 2] = w2 / s;
    }
}

// ---------------- gather (+ base + relu): out = relu(gather(feat) + base) ----
// XCD-swizzled: consecutive same-nb blocks co-locate per XCD (feat stays in L2).
template <int C, int NS, bool FUSE>
__global__ __launch_bounds__(256) void gather_kernel(
    const float* __restrict__ feat,                              // (NB, C, NS)
    const int* __restrict__ idx, const float* __restrict__ wgt,  // (B, Nu, 3)
    const float* __restrict__ basep,                             // (B, C, Nu)
    float* __restrict__ out, int Nu, int Q)                      // (NB, C, Nu)
{
    __shared__ __align__(16) float rows[8 * NS];
    const int tid = threadIdx.x;
    int f = blockIdx.x;
    int j = (f & 7) * ((int)gridDim.x >> 3) + (f >> 3);
    const int ntiles = Nu >> 8;
    const int nb = j / ntiles;
    const int nt = j % ntiles;
    const int n = nt * 256 + tid;
    const int b = nb / Q;
    size_t nnb = ((size_t)b * Nu + n) * 3;
    const int j0 = idx[nnb], j1 = idx[nnb + 1], j2 = idx[nnb + 2];
    const float w0 = wgt[nnb], w1 = wgt[nnb + 1], w2 = wgt[nnb + 2];
    const float* fbase = feat + (size_t)nb * C * NS;
    float* obase = out + (size_t)nb * C * Nu + n;
    const float* bbase = FUSE ? (basep + (size_t)b * C * Nu + n) : nullptr;
    for (int cc = 0; cc < C; cc += 8) {
        __syncthreads();
        const float4* src = reinterpret_cast<const float4*>(fbase + (size_t)cc * NS);
        float4* dst = reinterpret_cast<float4*>(rows);
        for (int i = tid; i < 2 * NS; i += 256) dst[i] = src[i];
        __syncthreads();
#pragma unroll
        for (int r = 0; r < 8; ++r) {
            const float* rp = rows + r * NS;
            float v = w0 * rp[j0] + w1 * rp[j1] + w2 * rp[j2];
            if constexpr (FUSE) {
                v += bbase[(size_t)(cc + r) * Nu];
                v = fmaxf(v, 0.f);
            }
            obase[(size_t)(cc + r) * Nu] = v;
        }
    }
}

// ---------------- prep (transpose+fold BN) + composite adapters ----------------
struct LayerDesc {
    const float* W; const float* b; const float* bn;
    float* wt; float* shb; int O; int C;
};
struct PCArgs {
    LayerDesc l[6];
    const float* a2w; const float* a2b; const float* w3; const float* b3; const float* bn3;
    float* w3c; float* sh3;
    const float* a1w; const float* a1b; const float* w5; const float* b5; const float* bn5;
    float* w5c; float* sh5;
};

__global__ __launch_bounds__(256) void prep_compose_kernel(PCArgs a) {
    const int bx = blockIdx.x, tid = threadIdx.x;
    if (bx < 96) {
        LayerDesc d = a.l[bx / 16];
        int sub = bx % 16;
        int total = d.O * d.C;
        for (int i = sub * 256 + tid; i < total; i += 16 * 256) {
            int c = i / d.O, o = i - (i / d.O) * d.O;
            float sc = 1.f;
            if (d.bn) { float g = d.bn[o], v = d.bn[3 * d.O + o]; sc = g * rsqrtf(v + EPS_BN); }
            d.wt[i] = d.W[(size_t)o * d.C + c] * sc;
        }
        for (int o = sub * 256 + tid; o < d.O; o += 16 * 256) {
            float sc = 1.f, sh = 0.f;
            if (d.bn) {
                float g = d.bn[o], be = d.bn[d.O + o], m = d.bn[2 * d.O + o], v = d.bn[3 * d.O + o];
                sc = g * rsqrtf(v + EPS_BN); sh = be - m * sc;
            }
            d.shb[o] = d.b[o] * sc + sh;
        }
    } else if (bx < 169) {
        int e = (bx - 96) * 256 + tid;
        if (e < 128 * 144) {
            int k = e / 144, o = e - (e / 144) * 144;
            float sc = a.bn3[o] * rsqrtf(a.bn3[3 * 144 + o] + EPS_BN);
            float s = 0.f;
            for (int c = 0; c < 144; ++c)
                s += a.a2w[c * 128 + k] * a.w3[(size_t)o * 288 + 144 + c];
            a.w3c[k * 144 + o] = s * sc;
        } else if (e < 128 * 144 + 144) {
            int o = e - 128 * 144;
            float g = a.bn3[o], be = a.bn3[144 + o], m = a.bn3[2 * 144 + o], v = a.bn3[3 * 144 + o];
            float sc = g * rsqrtf(v + EPS_BN);
            float s = 0.f;
            for (int c = 0; c < 144; ++c) s += a.w3[(size_t)o * 288 + 144 + c] * a.a2b[c];
            a.sh3[o] = (s + a.b3[o] - m) * sc + be;
        }
    } else {
        int e = (bx - 169) * 256 + tid;
        if (e < 3 * 72) {
            int k = e / 72, o = e - (e / 72) * 72;
            float sc = a.bn5[o] * rsqrtf(a.bn5[3 * 72 + o] + EPS_BN);
            float s = 0.f;
            for (int c = 0; c < 72; ++c)
                s += a.a1w[c * 3 + k] * a.w5[(size_t)o * 144 + 72 + c];
            a.w5c[k * 72 + o] = s * sc;
        } else if (e < 3 * 72 + 72) {
            int o = e - 3 * 72;
            float g = a.bn5[o], be = a.bn5[72 + o], m = a.bn5[2 * 72 + o], v = a.bn5[3 * 72 + o];
            float sc = g * rsqrtf(v + EPS_BN);
            float s = 0.f;
            for (int c = 0; c < 72; ++c) s += a.w5[(size_t)o * 144 + 72 + c] * a.a1b[c];
            a.sh5[o] = (s + a.b5[o] - m) * sc + be;
        }
    }
}

// ---------------- conv body: ADD 0=none, 1=shb, 2=base ----------------
template <int BLK, int CT, int O, int OT, int VEC, bool RELU, int ADD>
__device__ __forceinline__ void conv_body(
    int nt, int ot, int nb, int tid,
    const float* __restrict__ src0, int qdiv0,
    const float* __restrict__ Wt, const float* __restrict__ shb,
    const float* __restrict__ basep, int qdivb,
    float* __restrict__ outp, int N, float* wlds)
{
    const int oBase = ot * OT;
    const int n0 = (nt * BLK + tid) * VEC;

    for (int i = tid; i < CT * OT; i += BLK)
        wlds[i] = Wt[(size_t)(i / OT) * O + oBase + (i % OT)];
    __syncthreads();

    const float* s0 = src0 + (size_t)(nb / qdiv0) * CT * N + n0;

    float acc[OT][VEC];
#pragma unroll
    for (int ol = 0; ol < OT; ++ol)
#pragma unroll
        for (int j = 0; j < VEC; ++j) acc[ol][j] = 0.f;

    auto loadrow = [&](float (&x)[VEC], int c) {
        const float* p = s0 + (size_t)c * N;
        if constexpr (VEC == 4) {
            float4 t = *reinterpret_cast<const float4*>(p);
            x[0] = t.x; x[1] = t.y; x[2] = t.z; x[3] = t.w;
        } else if constexpr (VEC == 2) {
            float2 t = *reinterpret_cast<const float2*>(p);
            x[0] = t.x; x[1] = t.y;
        } else {
            x[0] = *p;
        }
    };
    auto comprow = [&](const float (&x)[VEC], int c) {
        if constexpr (OT >= 4) {
#pragma unroll
            for (int g = 0; g < OT / 4; ++g) {
                float4 wv = *reinterpret_cast<const float4*>(&wlds[c * OT + g * 4]);
                float ww[4] = {wv.x, wv.y, wv.z, wv.w};
#pragma unroll
                for (int r = 0; r < 4; ++r)
#pragma unroll
                    for (int j = 0; j < VEC; ++j)
                        acc[g * 4 + r][j] += ww[r] * x[j];
            }
        } else {
#pragma unroll
            for (int ol = 0; ol < OT; ++ol) {
                float w = wlds[c * OT + ol];
#pragma unroll
                for (int j = 0; j < VEC; ++j) acc[ol][j] += w * x[j];
            }
        }
    };
    auto loadg = [&](float (&buf)[4][VEC], int c) {
#pragma unroll
        for (int q = 0; q < 4; ++q) loadrow(buf[q], c + q);
    };
    auto compg = [&](const float (&buf)[4][VEC], int c) {
#pragma unroll
        for (int q = 0; q < 4; ++q) comprow(buf[q], c + q);
    };

    if constexpr (CT == 3) {
        float xs[3][VEC];
        loadrow(xs[0], 0); loadrow(xs[1], 1); loadrow(xs[2], 2);
        comprow(xs[0], 0); comprow(xs[1], 1); comprow(xs[2], 2);
    } else {
        static_assert(CT % 8 == 0 || CT % 8 == 4, "CT pipeline tail");
        float xa[4][VEC], xb[4][VEC];
        loadg(xa, 0); loadg(xb, 4);
        int c = 0;
#pragma unroll 1
        for (; c + 16 <= CT; c += 8) {
            compg(xa, c);     loadg(xa, c + 8);
            compg(xb, c + 4); loadg(xb, c + 12);
        }
        compg(xa, c);
        if constexpr (CT % 8 == 4) {
            loadg(xa, c + 8);
            compg(xb, c + 4);
            compg(xa, c + 8);
        } else {
            compg(xb, c + 4);
        }
    }

    const float* bp = (ADD == 2) ? (basep + ((size_t)(nb / qdivb) * O + oBase) * N + n0) : nullptr;
#pragma unroll
    for (int ol = 0; ol < OT; ++ol) {
        int o = oBase + ol;
        float addv[VEC];
        if constexpr (ADD == 2) {
            const float* p = bp + (size_t)ol * N;
            if constexpr (VEC == 4) {
                float4 t = *reinterpret_cast<const float4*>(p);
                addv[0] = t.x; addv[1] = t.y; addv[2] = t.z; addv[3] = t.w;
            } else if constexpr (VEC == 2) {
                float2 t = *reinterpret_cast<const float2*>(p);
                addv[0] = t.x; addv[1] = t.y;
            } else addv[0] = *p;
        } else if constexpr (ADD == 1) {
            float sb = shb[o];
#pragma unroll
            for (int j = 0; j < VEC; ++j) addv[j] = sb;
        } else {
#pragma unroll
            for (int j = 0; j < VEC; ++j) addv[j] = 0.f;
        }
        float res[VEC];
#pragma unroll
        for (int j = 0; j < VEC; ++j) {
            float y = acc[ol][j] + addv[j];
            if constexpr (RELU) y = fmaxf(y, 0.f);
            res[j] = y;
        }
        float* op = outp + ((size_t)nb * O + o) * N + n0;
        if constexpr (VEC == 4) {
            float4 t; t.x = res[0]; t.y = res[1]; t.z = res[2]; t.w = res[3];
            *reinterpret_cast<float4*>(op) = t;
        } else if constexpr (VEC == 2) {
            float2 t; t.x = res[0]; t.y = res[1];
            *reinterpret_cast<float2*>(op) = t;
        } else {
            *op = res[0];
        }
    }
}

// main convs: flat grid, XCD-bijective swizzle, o-tile innermost
template <int BLK, int CT, int O, int OT, int VEC, bool RELU, int ADD>
__global__ __launch_bounds__(BLK) void conv_swz(
    const float* __restrict__ src0, int qdiv0,
    const float* __restrict__ Wt, const float* __restrict__ shb,
    const float* __restrict__ basep, int qdivb,
    float* __restrict__ outp, int N, int GX, int GY)
{
    __shared__ __align__(16) float wlds[CT * OT];
    int f = blockIdx.x;
    int J = gridDim.x >> 3;
    int j = (f & 7) * J + (f >> 3);
    int ot = j % GY; int r = j / GY;
    int nt = r % GX; int nb = r / GX;
    conv_body<BLK, CT, O, OT, VEC, RELU, ADD>(
        nt, ot, nb, threadIdx.x, src0, qdiv0, Wt, shb, basep, qdivb, outp, N, wlds);
}

// merged per-b base GEMMs: [0,148)=base1, [148,436)=base3, [436,1012)=base5
__global__ __launch_bounds__(64) void bases_kernel(
    const float* __restrict__ x, const float* __restrict__ sa1f, const float* __restrict__ sa0f,
    const float* __restrict__ wt1, const float* __restrict__ sb1,
    const float* __restrict__ w3c, const float* __restrict__ sh3,
    const float* __restrict__ w5c, const float* __restrict__ sh5,
    float* __restrict__ base1, float* __restrict__ base3, float* __restrict__ base5)
{
    __shared__ __align__(16) float wlds[288 * 4];
    const int bx = blockIdx.x, tid = threadIdx.x;
    if (bx < 148) {
        int ot = bx % 74, nb = bx / 74;
        conv_body<64, 288, 296, 4, 4, false, 1>(0, ot, nb, tid, x, 1, wt1, sb1, nullptr, 1, base1, 256, wlds);
    } else if (bx < 436) {
        int lb = bx - 148;
        int nt = lb % 4, ot = (lb / 4) % 36, nb = lb / 144;
        conv_body<64, 128, 144, 4, 4, false, 1>(nt, ot, nb, tid, sa1f, 1, w3c, sh3, nullptr, 1, base3, 1024, wlds);
    } else {
        int lb = bx - 436;
        int nt = lb % 16, ot = (lb / 16) % 18, nb = lb / 288;
        conv_body<64, 3, 72, 4, 4, false, 1>(nt, ot, nb, tid, sa0f, 1, w5c, sh5, nullptr, 1, base5, 4096, wlds);
    }
}

// ---------------- fused h6 + out ----------------
__global__ __launch_bounds__(64) void h6_out_kernel(
    const float* __restrict__ src,   // (NB, 72, N)
    const float* __restrict__ Wt6,   // [72][36] scale-folded
    const float* __restrict__ shb6,  // [36]
    const float* __restrict__ wout, const float* __restrict__ bout,
    float* __restrict__ outp, int N)
{
    __shared__ __align__(16) float wlds[72 * 36];
    __shared__ float ow[36], shs[36];
    const int tid = threadIdx.x;
    for (int i = tid; i < 72 * 36; i += 64) wlds[i] = Wt6[i];
    if (tid < 36) { ow[tid] = wout[tid]; shs[tid] = shb6[tid]; }
    __syncthreads();
    const int nb = blockIdx.z;
    const int n0 = (blockIdx.x * 64 + tid) * 2;
    const float* s0 = src + (size_t)nb * 72 * N + n0;

    float acc[36][2];
#pragma unroll
    for (int ol = 0; ol < 36; ++ol) { acc[ol][0] = 0.f; acc[ol][1] = 0.f; }

    auto loadrow = [&](float (&x)[2], int c) {
        float2 t = *reinterpret_cast<const float2*>(s0 + (size_t)c * N);
        x[0] = t.x; x[1] = t.y;
    };
    auto comprow = [&](const float (&x)[2], int c) {
#pragma unroll
        for (int g = 0; g < 9; ++g) {
            float4 wv = *reinterpret_cast<const float4*>(&wlds[c * 36 + g * 4]);
            float ww[4] = {wv.x, wv.y, wv.z, wv.w};
#pragma unroll
            for (int r = 0; r < 4; ++r) {
                acc[g * 4 + r][0] += ww[r] * x[0];
                acc[g * 4 + r][1] += ww[r] * x[1];
            }
        }
    };
    float xa[4][2], xb[4][2];
    auto loadg = [&](float (&buf)[4][2], int c) {
#pragma unroll
        for (int q = 0; q < 4; ++q) loadrow(buf[q], c + q);
    };
    auto compg = [&](const float (&buf)[4][2], int c) {
#pragma unroll
        for (int q = 0; q < 4; ++q) comprow(buf[q], c + q);
    };
    loadg(xa, 0); loadg(xb, 4);
    int c = 0;
#pragma unroll 1
    for (; c + 16 <= 72; c += 8) {
        compg(xa, c);     loadg(xa, c + 8);
        compg(xb, c + 4); loadg(xb, c + 12);
    }
    compg(xa, c); compg(xb, c + 4);

    float bo = bout[0];
    float r0 = bo, r1 = bo;
#pragma unroll
    for (int ol = 0; ol < 36; ++ol) {
        float y0 = fmaxf(acc[ol][0] + shs[ol], 0.f);
        float y1 = fmaxf(acc[ol][1] + shs[ol], 0.f);
        r0 += ow[ol] * y0; r1 += ow[ol] * y1;
    }
    float2 t; t.x = r0; t.y = r1;
    *reinterpret_cast<float2*>(outp + (size_t)nb * N + n0) = t;
}

extern "C" void kernel_launch(void* const* d_in, const int* in_sizes, int n_in,
                              void* d_out, int out_size, void* d_ws, size_t ws_size,
                              hipStream_t stream) {
    const int B = 2, Q = 16, N0 = 4096, N1 = 1024, N2 = 256;
    const int I1 = 144, I2 = 72;
    const int NB = B * Q;  // 32

    const float* x     = (const float*)d_in[0];
    const float* mask  = (const float*)d_in[1];
    const float* sa0f  = (const float*)d_in[2];
    const float* sa1f  = (const float*)d_in[3];
    const float* xyz0  = (const float*)d_in[4];
    const float* xyz1  = (const float*)d_in[5];
    const float* xyz2  = (const float*)d_in[6];

    float* ws = (float*)d_ws;
    size_t off = 0;
    auto alloc = [&](size_t n) { size_t p = off; off += (n + 15) & ~(size_t)15; return p; };

    size_t wgt1  = alloc((size_t)B * N1 * 3);
    size_t wgt2  = alloc((size_t)B * N0 * 3);
    size_t idx1  = alloc((size_t)B * N1 * 3);
    size_t idx2  = alloc((size_t)B * N0 * 3);
    size_t slotA = alloc((size_t)NB * I2 * N0);   // h1 / g3 / h4 / h5
    size_t slotB = alloc((size_t)NB * I1 * N1);   // h2 / h3 / g5
    size_t base1 = alloc((size_t)B * 296 * N2);
    size_t base3 = alloc((size_t)B * I1 * N1);
    size_t base5 = alloc((size_t)B * I2 * N0);
    size_t wt1 = alloc(296 * 296), sb1 = alloc(296);
    size_t wt2 = alloc(296 * 144), sb2 = alloc(144);
    size_t wt3 = alloc(288 * 144), sb3 = alloc(144);
    size_t wt4 = alloc(144 * 72),  sb4 = alloc(72);
    size_t wt5 = alloc(144 * 72),  sb5 = alloc(72);
    size_t wt6 = alloc(72 * 36),   sb6 = alloc(36);
    size_t w3c = alloc(128 * 144), sh3 = alloc(144);
    size_t w5c = alloc(3 * 72),    sh5 = alloc(72);
    (void)ws_size; (void)in_sizes; (void)n_in;

    auto din = [&](int i) { return (const float*)d_in[i]; };

    PCArgs pa;
    pa.l[0] = { din(7),  din(8),  din(9),  ws + wt1, ws + sb1, 296, 296 };
    pa.l[1] = { din(10), din(11), din(12), ws + wt2, ws + sb2, 144, 296 };
    pa.l[2] = { din(17), din(18), din(19), ws + wt3, ws + sb3, 144, 288 };
    pa.l[3] = { din(20), din(21), din(22), ws + wt4, ws + sb4, 72, 144 };
    pa.l[4] = { din(23), din(24), din(25), ws + wt5, ws + sb5, 72, 144 };
    pa.l[5] = { din(26), din(27), din(28), ws + wt6, ws + sb6, 36, 72 };
    pa.a2w = din(15); pa.a2b = din(16); pa.w3 = din(17); pa.b3 = din(18); pa.bn3 = din(19);
    pa.w3c = ws + w3c; pa.sh3 = ws + sh3;
    pa.a1w = din(13); pa.a1b = din(14); pa.w5 = din(23); pa.b5 = din(24); pa.bn5 = din(25);
    pa.w5c = ws + w5c; pa.sh5 = ws + sh5;
    prep_compose_kernel<<<dim3(171), 256, 0, stream>>>(pa);

    three_nn2_kernel<<<dim3(160, B), 512, 0, stream>>>(
        xyz0, xyz1, xyz2, (int*)(ws + idx1), ws + wgt1, (int*)(ws + idx2), ws + wgt2);

    // per-b bases (base1 | base3 | base5), OT=4 -> 1012 waves
    bases_kernel<<<dim3(1012), 64, 0, stream>>>(
        x, sa1f, sa0f, ws + wt1, ws + sb1, ws + w3c, ws + sh3, ws + w5c, ws + sh5,
        ws + base1, ws + base3, ws + base5);

    // h1 = ReLU(W1[:,288:] @ mask + base1) -> slotA   [2368 blocks]
    conv_swz<64, 8, 296, 4, 4, true, 2><<<dim3(2368), 64, 0, stream>>>(
        mask, 1, ws + wt1 + 288 * 296, ws + sb1, ws + base1, Q, ws + slotA, N2, 1, 74);

    // h2 = layer2(h1) -> slotB   [1152 blocks]
    conv_swz<64, 296, 144, 4, 4, true, 1><<<dim3(1152), 64, 0, stream>>>(
        ws + slotA, 1, ws + wt2, ws + sb2, nullptr, 1, ws + slotB, N2, 1, 36);

    // g3 = W3a @ h2 (N=256, shift-free) -> slotA   [1152 blocks]
    conv_swz<64, 144, 144, 4, 4, false, 0><<<dim3(1152), 64, 0, stream>>>(
        ws + slotB, 1, ws + wt3, ws + sb3, nullptr, 1, ws + slotA, N2, 1, 36);

    // h3 = ReLU(gather(g3) + base3) -> slotB   [128 blocks]
    gather_kernel<144, 256, true><<<dim3(128), 256, 0, stream>>>(
        ws + slotA, (const int*)(ws + idx1), ws + wgt1, ws + base3, ws + slotB, N1, Q);

    // h4 = ReLU(W4 @ h3 + shb4) -> slotA   [2304 blocks]
    conv_swz<64, 144, 72, 4, 4, true, 1><<<dim3(2304), 64, 0, stream>>>(
        ws + slotB, 1, ws + wt4, ws + sb4, nullptr, 1, ws + slotA, N1, 4, 18);

    // g5 = W5a @ h4 (N=1024, shift-free) -> slotB   [2304 blocks]
    conv_swz<64, 72, 72, 4, 4, false, 0><<<dim3(2304), 64, 0, stream>>>(
        ws + slotA, 1, ws + wt5, ws + sb5, nullptr, 1, ws + slotB, N1, 4, 18);

    // h5 = ReLU(gather(g5) + base5) -> slotA   [512 blocks]
    gather_kernel<72, 1024, true><<<dim3(512), 256, 0, stream>>>(
        ws + slotB, (const int*)(ws + idx2), ws + wgt2, ws + base5, ws + slotA, N0, Q);

    // fused h6 + out -> d_out   [1024 blocks]
    h6_out_kernel<<<dim3(32, 1, NB), 64, 0, stream>>>(
        ws + slotA, ws + wt6, ws + sb6, din(29), din(30), (float*)d_out, N0);
}

// Round 11
// 198.427 us; speedup vs baseline: 1.6930x; 1.0819x over previous
//
#include <hip/hip_runtime.h>

#define EPS_BN 1e-5f

// ---------------- prep/compose + three_nn merged (independent work) --------
struct LayerDesc {
    const float* W; const float* b; const float* bn;
    float* wt; float* shb; int O; int C;
};
struct HeadArgs {
    LayerDesc l[6];
    const float* a2w; const float* a2b; const float* w3; const float* b3; const float* bn3;
    float* w3c; float* sh3;
    const float* a1w; const float* a1b; const float* w5; const float* b5; const float* bn5;
    float* w5c; float* sh5;
    const float* xyz0; const float* xyz1; const float* xyz2;
    int* idx1; float* wgt1; int* idx2; float* wgt2;
};

__global__ __launch_bounds__(256) void head_kernel(HeadArgs a) {
    const int bx = blockIdx.x, tid = threadIdx.x;
    if (bx < 96) {
        LayerDesc d = a.l[bx / 16];
        int sub = bx % 16;
        int total = d.O * d.C;
        for (int i = sub * 256 + tid; i < total; i += 16 * 256) {
            int c = i / d.O, o = i - (i / d.O) * d.O;
            float sc = 1.f;
            if (d.bn) { float g = d.bn[o], v = d.bn[3 * d.O + o]; sc = g * rsqrtf(v + EPS_BN); }
            d.wt[i] = d.W[(size_t)o * d.C + c] * sc;
        }
        for (int o = sub * 256 + tid; o < d.O; o += 16 * 256) {
            float sc = 1.f, sh = 0.f;
            if (d.bn) {
                float g = d.bn[o], be = d.bn[d.O + o], m = d.bn[2 * d.O + o], v = d.bn[3 * d.O + o];
                sc = g * rsqrtf(v + EPS_BN); sh = be - m * sc;
            }
            d.shb[o] = d.b[o] * sc + sh;
        }
        return;
    } else if (bx < 169) {
        int e = (bx - 96) * 256 + tid;
        if (e < 128 * 144) {
            int k = e / 144, o = e - (e / 144) * 144;
            float sc = a.bn3[o] * rsqrtf(a.bn3[3 * 144 + o] + EPS_BN);
            float s = 0.f;
            for (int c = 0; c < 144; ++c)
                s += a.a2w[c * 128 + k] * a.w3[(size_t)o * 288 + 144 + c];
            a.w3c[k * 144 + o] = s * sc;
        } else if (e < 128 * 144 + 144) {
            int o = e - 128 * 144;
            float g = a.bn3[o], be = a.bn3[144 + o], m = a.bn3[2 * 144 + o], v = a.bn3[3 * 144 + o];
            float sc = g * rsqrtf(v + EPS_BN);
            float s = 0.f;
            for (int c = 0; c < 144; ++c) s += a.w3[(size_t)o * 288 + 144 + c] * a.a2b[c];
            a.sh3[o] = (s + a.b3[o] - m) * sc + be;
        }
        return;
    } else if (bx < 171) {
        int e = (bx - 169) * 256 + tid;
        if (e < 3 * 72) {
            int k = e / 72, o = e - (e / 72) * 72;
            float sc = a.bn5[o] * rsqrtf(a.bn5[3 * 72 + o] + EPS_BN);
            float s = 0.f;
            for (int c = 0; c < 72; ++c)
                s += a.a1w[c * 3 + k] * a.w5[(size_t)o * 144 + 72 + c];
            a.w5c[k * 72 + o] = s * sc;
        } else if (e < 3 * 72 + 72) {
            int o = e - 3 * 72;
            float g = a.bn5[o], be = a.bn5[72 + o], m = a.bn5[2 * 72 + o], v = a.bn5[3 * 72 + o];
            float sc = g * rsqrtf(v + EPS_BN);
            float s = 0.f;
            for (int c = 0; c < 72; ++c) s += a.w5[(size_t)o * 144 + 72 + c] * a.a1b[c];
            a.sh5[o] = (s + a.b5[o] - m) * sc + be;
        }
        return;
    }
    // ---- three_nn part: 256 threads = 32 unknowns x 8 segments ----
    const int NSEG = 8;
    __shared__ float kl[3 * 1024];
    __shared__ float sd[NSEG][32][3];
    __shared__ int   si[NSEG][32][3];
    const float* unknown; const float* known;
    int Nu, Nk, blk, b; int* idx; float* wgt;
    int t = bx - 171;
    if (t < 64) {
        unknown = a.xyz1; known = a.xyz2; Nu = 1024; Nk = 256;
        b = t >> 5; blk = t & 31; idx = a.idx1; wgt = a.wgt1;
    } else {
        t -= 64;
        unknown = a.xyz0; known = a.xyz1; Nu = 4096; Nk = 1024;
        b = t >> 7; blk = t & 127; idx = a.idx2; wgt = a.wgt2;
    }
    for (int i = tid; i < Nk * 3; i += 256) kl[i] = known[(size_t)b * Nk * 3 + i];
    __syncthreads();
    const int u   = tid & 31;
    const int seg = tid >> 5;
    const int n   = blk * 32 + u;
    const float* up = unknown + ((size_t)b * Nu + n) * 3;
    const float ux = up[0], uy = up[1], uz = up[2];
    float d0 = 1e30f, d1 = 1e30f, d2 = 1e30f;
    int i0 = 0, i1 = 0, i2 = 0;
    const int klo = seg * (Nk / NSEG), khi = klo + Nk / NSEG;
    for (int k = klo; k < khi; ++k) {
        float dx = __fsub_rn(ux, kl[3 * k + 0]);
        float dy = __fsub_rn(uy, kl[3 * k + 1]);
        float dz = __fsub_rn(uz, kl[3 * k + 2]);
        float d = __fadd_rn(__fadd_rn(__fmul_rn(dx, dx), __fmul_rn(dy, dy)), __fmul_rn(dz, dz));
        if (d < d0)      { d2 = d1; i2 = i1; d1 = d0; i1 = i0; d0 = d; i0 = k; }
        else if (d < d1) { d2 = d1; i2 = i1; d1 = d;  i1 = k; }
        else if (d < d2) { d2 = d;  i2 = k; }
    }
    sd[seg][u][0] = d0; sd[seg][u][1] = d1; sd[seg][u][2] = d2;
    si[seg][u][0] = i0; si[seg][u][1] = i1; si[seg][u][2] = i2;
    __syncthreads();
    if (tid < 32) {
        float m0 = 1e30f, m1 = 1e30f, m2 = 1e30f;
        int j0 = 0, j1 = 0, j2 = 0;
        for (int s = 0; s < NSEG; ++s)
            for (int c = 0; c < 3; ++c) {
                float d = sd[s][u][c];
                int ii = si[s][u][c];
                if (d < m0)      { m2 = m1; j2 = j1; m1 = m0; j1 = j0; m0 = d; j0 = ii; }
                else if (d < m1) { m2 = m1; j2 = j1; m1 = d;  j1 = ii; }
                else if (d < m2) { m2 = d;  j2 = ii; }
            }
        float w0 = 1.f / (m0 + 1e-8f), w1 = 1.f / (m1 + 1e-8f), w2 = 1.f / (m2 + 1e-8f);
        float s = w0 + w1 + w2;
        size_t base = ((size_t)b * Nu + n) * 3;
        idx[base + 0] = j0; idx[base + 1] = j1; idx[base + 2] = j2;
        wgt[base + 0] = w0 / s; wgt[base + 1] = w1 / s; wgt[base + 2] = w2 / s;
    }
}

// ---------------- gather (+ base + relu) ----------------
template <int C, int NS, bool FUSE>
__global__ __launch_bounds__(256) void gather_kernel(
    const float* __restrict__ feat,
    const int* __restrict__ idx, const float* __restrict__ wgt,
    const float* __restrict__ basep,
    float* __restrict__ out, int Nu, int Q)
{
    __shared__ __align__(16) float rows[8 * NS];
    const int tid = threadIdx.x;
    int f = blockIdx.x;
    int j = (f & 7) * ((int)gridDim.x >> 3) + (f >> 3);
    const int ntiles = Nu >> 8;
    const int nb = j / ntiles;
    const int nt = j % ntiles;
    const int n = nt * 256 + tid;
    const int b = nb / Q;
    size_t nnb = ((size_t)b * Nu + n) * 3;
    const int j0 = idx[nnb], j1 = idx[nnb + 1], j2 = idx[nnb + 2];
    const float w0 = wgt[nnb], w1 = wgt[nnb + 1], w2 = wgt[nnb + 2];
    const float* fbase = feat + (size_t)nb * C * NS;
    float* obase = out + (size_t)nb * C * Nu + n;
    const float* bbase = FUSE ? (basep + (size_t)b * C * Nu + n) : nullptr;
    for (int cc = 0; cc < C; cc += 8) {
        __syncthreads();
        const float4* src = reinterpret_cast<const float4*>(fbase + (size_t)cc * NS);
        float4* dst = reinterpret_cast<float4*>(rows);
        for (int i = tid; i < 2 * NS; i += 256) dst[i] = src[i];
        __syncthreads();
#pragma unroll
        for (int r = 0; r < 8; ++r) {
            const float* rp = rows + r * NS;
            float v = w0 * rp[j0] + w1 * rp[j1] + w2 * rp[j2];
            if constexpr (FUSE) {
                v += bbase[(size_t)(cc + r) * Nu];
                v = fmaxf(v, 0.f);
            }
            obase[(size_t)(cc + r) * Nu] = v;
        }
    }
}

// ---------------- conv body: ADD 0=none, 1=shb, 2=base ----------------
template <int BLK, int CT, int O, int OT, int VEC, bool RELU, int ADD>
__device__ __forceinline__ void conv_body(
    int nt, int ot, int nb, int tid,
    const float* __restrict__ src0, int qdiv0,
    const float* __restrict__ Wt, const float* __restrict__ shb,
    const float* __restrict__ basep, int qdivb,
    float* __restrict__ outp, int N, float* wlds)
{
    const int oBase = ot * OT;
    const int n0 = (nt * BLK + tid) * VEC;

    for (int i = tid; i < CT * OT; i += BLK)
        wlds[i] = Wt[(size_t)(i / OT) * O + oBase + (i % OT)];
    __syncthreads();

    const float* s0 = src0 + (size_t)(nb / qdiv0) * CT * N + n0;

    float acc[OT][VEC];
#pragma unroll
    for (int ol = 0; ol < OT; ++ol)
#pragma unroll
        for (int j = 0; j < VEC; ++j) acc[ol][j] = 0.f;

    auto loadrow = [&](float (&x)[VEC], int c) {
        const float* p = s0 + (size_t)c * N;
        if constexpr (VEC == 4) {
            float4 t = *reinterpret_cast<const float4*>(p);
            x[0] = t.x; x[1] = t.y; x[2] = t.z; x[3] = t.w;
        } else if constexpr (VEC == 2) {
            float2 t = *reinterpret_cast<const float2*>(p);
            x[0] = t.x; x[1] = t.y;
        } else {
            x[0] = *p;
        }
    };
    auto comprow = [&](const float (&x)[VEC], int c) {
        if constexpr (OT >= 4) {
#pragma unroll
            for (int g = 0; g < OT / 4; ++g) {
                float4 wv = *reinterpret_cast<const float4*>(&wlds[c * OT + g * 4]);
                float ww[4] = {wv.x, wv.y, wv.z, wv.w};
#pragma unroll
                for (int r = 0; r < 4; ++r)
#pragma unroll
                    for (int j = 0; j < VEC; ++j)
                        acc[g * 4 + r][j] += ww[r] * x[j];
            }
        } else {
#pragma unroll
            for (int ol = 0; ol < OT; ++ol) {
                float w = wlds[c * OT + ol];
#pragma unroll
                for (int j = 0; j < VEC; ++j) acc[ol][j] += w * x[j];
            }
        }
    };
    auto loadg = [&](float (&buf)[4][VEC], int c) {
#pragma unroll
        for (int q = 0; q < 4; ++q) loadrow(buf[q], c + q);
    };
    auto compg = [&](const float (&buf)[4][VEC], int c) {
#pragma unroll
        for (int q = 0; q < 4; ++q) comprow(buf[q], c + q);
    };

    if constexpr (CT == 3) {
        float xs[3][VEC];
        loadrow(xs[0], 0); loadrow(xs[1], 1); loadrow(xs[2], 2);
        comprow(xs[0], 0); comprow(xs[1], 1); comprow(xs[2], 2);
    } else {
        static_assert(CT % 8 == 0 || CT % 8 == 4, "CT pipeline tail");
        float xa[4][VEC], xb[4][VEC];
        loadg(xa, 0); loadg(xb, 4);
        int c = 0;
#pragma unroll 1
        for (; c + 16 <= CT; c += 8) {
            compg(xa, c);     loadg(xa, c + 8);
            compg(xb, c + 4); loadg(xb, c + 12);
        }
        compg(xa, c);
        if constexpr (CT % 8 == 4) {
            loadg(xa, c + 8);
            compg(xb, c + 4);
            compg(xa, c + 8);
        } else {
            compg(xb, c + 4);
        }
    }

    const float* bp = (ADD == 2) ? (basep + ((size_t)(nb / qdivb) * O + oBase) * N + n0) : nullptr;
#pragma unroll
    for (int ol = 0; ol < OT; ++ol) {
        int o = oBase + ol;
        float addv[VEC];
        if constexpr (ADD == 2) {
            const float* p = bp + (size_t)ol * N;
            if constexpr (VEC == 4) {
                float4 t = *reinterpret_cast<const float4*>(p);
                addv[0] = t.x; addv[1] = t.y; addv[2] = t.z; addv[3] = t.w;
            } else if constexpr (VEC == 2) {
                float2 t = *reinterpret_cast<const float2*>(p);
                addv[0] = t.x; addv[1] = t.y;
            } else addv[0] = *p;
        } else if constexpr (ADD == 1) {
            float sb = shb[o];
#pragma unroll
            for (int j = 0; j < VEC; ++j) addv[j] = sb;
        } else {
#pragma unroll
            for (int j = 0; j < VEC; ++j) addv[j] = 0.f;
        }
        float res[VEC];
#pragma unroll
        for (int j = 0; j < VEC; ++j) {
            float y = acc[ol][j] + addv[j];
            if constexpr (RELU) y = fmaxf(y, 0.f);
            res[j] = y;
        }
        float* op = outp + ((size_t)nb * O + o) * N + n0;
        if constexpr (VEC == 4) {
            float4 t; t.x = res[0]; t.y = res[1]; t.z = res[2]; t.w = res[3];
            *reinterpret_cast<float4*>(op) = t;
        } else if constexpr (VEC == 2) {
            float2 t; t.x = res[0]; t.y = res[1];
            *reinterpret_cast<float2*>(op) = t;
        } else {
            *op = res[0];
        }
    }
}

template <int BLK, int CT, int O, int OT, int VEC, bool RELU, int ADD>
__global__ __launch_bounds__(BLK) void conv_swz(
    const float* __restrict__ src0, int qdiv0,
    const float* __restrict__ Wt, const float* __restrict__ shb,
    const float* __restrict__ basep, int qdivb,
    float* __restrict__ outp, int N, int GX, int GY)
{
    __shared__ __align__(16) float wlds[CT * OT];
    int f = blockIdx.x;
    int J = gridDim.x >> 3;
    int j = (f & 7) * J + (f >> 3);
    int ot = j % GY; int r = j / GY;
    int nt = r % GX; int nb = r / GX;
    conv_body<BLK, CT, O, OT, VEC, RELU, ADD>(
        nt, ot, nb, threadIdx.x, src0, qdiv0, Wt, shb, basep, qdivb, outp, N, wlds);
}

// per-b bases: [0,148)=base1, [148,436)=base3
__global__ __launch_bounds__(64) void bases_kernel(
    const float* __restrict__ x, const float* __restrict__ sa1f,
    const float* __restrict__ wt1, const float* __restrict__ sb1,
    const float* __restrict__ w3c, const float* __restrict__ sh3,
    float* __restrict__ base1, float* __restrict__ base3)
{
    __shared__ __align__(16) float wlds[288 * 4];
    const int bx = blockIdx.x, tid = threadIdx.x;
    if (bx < 148) {
        int ot = bx % 74, nb = bx / 74;
        conv_body<64, 288, 296, 4, 4, false, 1>(0, ot, nb, tid, x, 1, wt1, sb1, nullptr, 1, base1, 256, wlds);
    } else {
        int lb = bx - 148;
        int nt = lb % 4, ot = (lb / 4) % 36, nb = lb / 144;
        conv_body<64, 128, 144, 4, 4, false, 1>(nt, ot, nb, tid, sa1f, 1, w3c, sh3, nullptr, 1, base3, 1024, wlds);
    }
}

// ---------------- fused gather2 + base5 + h6 + out ----------------
// h5[c][n] = relu( w0*g5[c][j0]+w1*g5[c][j1]+w2*g5[c][j2]
//                  + sum_k w5c[k][c]*sa0[k][n] + sh5[c] )
// out[n]   = bout + sum_o wout[o]*relu( sum_c Wt6[c][o]*h5[c][n] + shb6[o] )
__global__ __launch_bounds__(64) void h6out_kernel(
    const float* __restrict__ g5,    // (NB, 72, 1024)
    const int* __restrict__ idx, const float* __restrict__ wgt,  // (B, 4096, 3)
    const float* __restrict__ sa0,   // (B, 3, 4096)
    const float* __restrict__ w5c, const float* __restrict__ sh5,   // [3][72], [72]
    const float* __restrict__ Wt6, const float* __restrict__ shb6,  // [72][36], [36]
    const float* __restrict__ wout, const float* __restrict__ bout,
    float* __restrict__ outp)        // (NB, 4096)
{
    __shared__ __align__(16) float wlds[72 * 36];
    __shared__ float w5l[3 * 72];
    __shared__ float sh5l[72], ow[36], sh6l[36];
    const int tid = threadIdx.x;
    for (int i = tid; i < 72 * 36; i += 64) wlds[i] = Wt6[i];
    for (int i = tid; i < 216; i += 64) w5l[i] = w5c[i];
    for (int i = tid; i < 72; i += 64) sh5l[i] = sh5[i];
    if (tid < 36) { ow[tid] = wout[tid]; sh6l[tid] = shb6[tid]; }
    __syncthreads();
    int f = blockIdx.x;
    int j = (f & 7) * ((int)gridDim.x >> 3) + (f >> 3);
    const int nb = j >> 6;            // 64 n-tiles per nb
    const int nt = j & 63;
    const int n = nt * 64 + tid;
    const int b = nb >> 4;            // Q=16
    size_t nn = ((size_t)b * 4096 + n) * 3;
    const int j0 = idx[nn], j1 = idx[nn + 1], j2 = idx[nn + 2];
    const float w0 = wgt[nn], w1 = wgt[nn + 1], w2 = wgt[nn + 2];
    const float* gb = g5 + (size_t)nb * 72 * 1024;
    const float* s0 = sa0 + (size_t)b * 3 * 4096 + n;
    const float sx = s0[0], sy = s0[4096], sz = s0[8192];

    float acc[36];
#pragma unroll
    for (int o = 0; o < 36; ++o) acc[o] = 0.f;

    float ra[4][3], rb[4][3];
    auto ld = [&](float (&r)[4][3], int c) {
#pragma unroll
        for (int q = 0; q < 4; ++q) {
            const float* rp = gb + (size_t)(c + q) * 1024;
            r[q][0] = rp[j0]; r[q][1] = rp[j1]; r[q][2] = rp[j2];
        }
    };
    auto cp = [&](const float (&r)[4][3], int c) {
#pragma unroll
        for (int q = 0; q < 4; ++q) {
            int cc = c + q;
            float base = w5l[cc] * sx + w5l[72 + cc] * sy + w5l[144 + cc] * sz + sh5l[cc];
            float xv = fmaxf(w0 * r[q][0] + w1 * r[q][1] + w2 * r[q][2] + base, 0.f);
#pragma unroll
            for (int g = 0; g < 9; ++g) {
                float4 wv = *reinterpret_cast<const float4*>(&wlds[cc * 36 + g * 4]);
                acc[g * 4 + 0] += wv.x * xv;
                acc[g * 4 + 1] += wv.y * xv;
                acc[g * 4 + 2] += wv.z * xv;
                acc[g * 4 + 3] += wv.w * xv;
            }
        }
    };
    ld(ra, 0); ld(rb, 4);
    int c = 0;
#pragma unroll 1
    for (; c + 16 <= 72; c += 8) {
        cp(ra, c);     ld(ra, c + 8);
        cp(rb, c + 4); ld(rb, c + 12);
    }
    cp(ra, c); cp(rb, c + 4);

    float r = bout[0];
#pragma unroll
    for (int o = 0; o < 36; ++o) r += ow[o] * fmaxf(acc[o] + sh6l[o], 0.f);
    outp[(size_t)nb * 4096 + n] = r;
}

extern "C" void kernel_launch(void* const* d_in, const int* in_sizes, int n_in,
                              void* d_out, int out_size, void* d_ws, size_t ws_size,
                              hipStream_t stream) {
    const int B = 2, Q = 16, N0 = 4096, N1 = 1024, N2 = 256;
    const int I1 = 144, I2 = 72;
    const int NB = B * Q;  // 32

    const float* x     = (const float*)d_in[0];
    const float* mask  = (const float*)d_in[1];
    const float* sa0f  = (const float*)d_in[2];
    const float* sa1f  = (const float*)d_in[3];
    const float* xyz0  = (const float*)d_in[4];
    const float* xyz1  = (const float*)d_in[5];
    const float* xyz2  = (const float*)d_in[6];

    float* ws = (float*)d_ws;
    size_t off = 0;
    auto alloc = [&](size_t n) { size_t p = off; off += (n + 15) & ~(size_t)15; return p; };

    size_t wgt1  = alloc((size_t)B * N1 * 3);
    size_t wgt2  = alloc((size_t)B * N0 * 3);
    size_t idx1  = alloc((size_t)B * N1 * 3);
    size_t idx2  = alloc((size_t)B * N0 * 3);
    size_t slotA = alloc((size_t)NB * 296 * N2);  // h1 / g3 / h4
    size_t slotB = alloc((size_t)NB * I1 * N1);   // h2 / h3 / g5
    size_t base1 = alloc((size_t)B * 296 * N2);
    size_t base3 = alloc((size_t)B * I1 * N1);
    size_t wt1 = alloc(296 * 296), sb1 = alloc(296);
    size_t wt2 = alloc(296 * 144), sb2 = alloc(144);
    size_t wt3 = alloc(288 * 144), sb3 = alloc(144);
    size_t wt4 = alloc(144 * 72),  sb4 = alloc(72);
    size_t wt5 = alloc(144 * 72),  sb5 = alloc(72);
    size_t wt6 = alloc(72 * 36),   sb6 = alloc(36);
    size_t w3c = alloc(128 * 144), sh3 = alloc(144);
    size_t w5c = alloc(3 * 72),    sh5 = alloc(72);
    (void)ws_size; (void)in_sizes; (void)n_in;

    auto din = [&](int i) { return (const float*)d_in[i]; };

    HeadArgs ha;
    ha.l[0] = { din(7),  din(8),  din(9),  ws + wt1, ws + sb1, 296, 296 };
    ha.l[1] = { din(10), din(11), din(12), ws + wt2, ws + sb2, 144, 296 };
    ha.l[2] = { din(17), din(18), din(19), ws + wt3, ws + sb3, 144, 288 };
    ha.l[3] = { din(20), din(21), din(22), ws + wt4, ws + sb4, 72, 144 };
    ha.l[4] = { din(23), din(24), din(25), ws + wt5, ws + sb5, 72, 144 };
    ha.l[5] = { din(26), din(27), din(28), ws + wt6, ws + sb6, 36, 72 };
    ha.a2w = din(15); ha.a2b = din(16); ha.w3 = din(17); ha.b3 = din(18); ha.bn3 = din(19);
    ha.w3c = ws + w3c; ha.sh3 = ws + sh3;
    ha.a1w = din(13); ha.a1b = din(14); ha.w5 = din(23); ha.b5 = din(24); ha.bn5 = din(25);
    ha.w5c = ws + w5c; ha.sh5 = ws + sh5;
    ha.xyz0 = xyz0; ha.xyz1 = xyz1; ha.xyz2 = xyz2;
    ha.idx1 = (int*)(ws + idx1); ha.wgt1 = ws + wgt1;
    ha.idx2 = (int*)(ws + idx2); ha.wgt2 = ws + wgt2;
    head_kernel<<<dim3(171 + 64 + 256), 256, 0, stream>>>(ha);

    // per-b bases (base1 | base3)
    bases_kernel<<<dim3(436), 64, 0, stream>>>(
        x, sa1f, ws + wt1, ws + sb1, ws + w3c, ws + sh3, ws + base1, ws + base3);

    // h1 = ReLU(W1[:,288:] @ mask + base1) -> slotA   [2368 blocks]
    conv_swz<64, 8, 296, 4, 4, true, 2><<<dim3(2368), 64, 0, stream>>>(
        mask, 1, ws + wt1 + 288 * 296, ws + sb1, ws + base1, Q, ws + slotA, N2, 1, 74);

    // h2 = layer2(h1) -> slotB   [1152 blocks]
    conv_swz<64, 296, 144, 4, 4, true, 1><<<dim3(1152), 64, 0, stream>>>(
        ws + slotA, 1, ws + wt2, ws + sb2, nullptr, 1, ws + slotB, N2, 1, 36);

    // g3 = W3a @ h2 (N=256) -> slotA   [1152 blocks]
    conv_swz<64, 144, 144, 4, 4, false, 0><<<dim3(1152), 64, 0, stream>>>(
        ws + slotB, 1, ws + wt3, ws + sb3, nullptr, 1, ws + slotA, N2, 1, 36);

    // h3 = ReLU(gather(g3) + base3) -> slotB   [128 blocks]
    gather_kernel<144, 256, true><<<dim3(128), 256, 0, stream>>>(
        ws + slotA, (const int*)(ws + idx1), ws + wgt1, ws + base3, ws + slotB, N1, Q);

    // h4 = ReLU(W4 @ h3 + shb4) -> slotA   [2304 blocks]
    conv_swz<64, 144, 72, 4, 4, true, 1><<<dim3(2304), 64, 0, stream>>>(
        ws + slotB, 1, ws + wt4, ws + sb4, nullptr, 1, ws + slotA, N1, 4, 18);

    // g5 = W5a @ h4 (N=1024) -> slotB   [2304 blocks]
    conv_swz<64, 72, 72, 4, 4, false, 0><<<dim3(2304), 64, 0, stream>>>(
        ws + slotA, 1, ws + wt5, ws + sb5, nullptr, 1, ws + slotB, N1, 4, 18);

    // fused gather2 + base5 + h6 + out -> d_out   [2048 blocks]
    h6out_kernel<<<dim3(2048), 64, 0, stream>>>(
        ws + slotB, (const int*)(ws + idx2), ws + wgt2, sa0f,
        ws + w5c, ws + sh5, ws + wt6, ws + sb6, din(29), din(30), (float*)d_out);
}